// Round 2
// baseline (1349.421 us; speedup 1.0000x reference)
//
#include <hip/hip_runtime.h>
#include <hip/hip_bf16.h>
#include <math.h>

#define B_  4
#define S_  2048
#define D_  2048
#define H_  16
#define G_  4
#define HD_ 128

typedef __attribute__((ext_vector_type(8))) short short8;
typedef __attribute__((ext_vector_type(4))) float floatx4;

__device__ __forceinline__ short f2bf(float f) {
    unsigned u = __float_as_uint(f);
    unsigned r = (u + 0x7fff + ((u >> 16) & 1)) >> 16;
    return (short)r;
}
__device__ __forceinline__ float b2f(short s) {
    return __uint_as_float(((unsigned)(unsigned short)s) << 16);
}
// pack two floats to bf16x2, round-half-up (cheap; used for P)
__device__ __forceinline__ unsigned pk2(float a, float b) {
    unsigned ua = (__float_as_uint(a) + 0x8000u) >> 16;
    unsigned ub = (__float_as_uint(b) + 0x8000u) & 0xffff0000u;
    return ua | ub;
}
// pack two floats to bf16x2, RNE (outputs)
__device__ __forceinline__ unsigned pkr(float a, float b) {
    return (unsigned)(unsigned short)f2bf(a) |
           ((unsigned)(unsigned short)f2bf(b) << 16);
}

#define GLL16(gp, lp) __builtin_amdgcn_global_load_lds( \
    (const __attribute__((address_space(1))) void*)(gp), \
    (__attribute__((address_space(3))) void*)(lp), 16, 0, 0)

// ---------------------------------------------------------------------------
// fp32 -> bf16 convert (8 elems/thread)
// ---------------------------------------------------------------------------
__global__ void cvt_bf16_kernel(const float* __restrict__ in,
                                short* __restrict__ out, int n8)
{
    int t = blockIdx.x * 256 + threadIdx.x;
    if (t >= n8) return;
    const float4* p = (const float4*)in + (size_t)t * 2;
    float4 a = p[0], b = p[1];
    short8 r;
    r[0] = f2bf(a.x); r[1] = f2bf(a.y); r[2] = f2bf(a.z); r[3] = f2bf(a.w);
    r[4] = f2bf(b.x); r[5] = f2bf(b.y); r[6] = f2bf(b.z); r[7] = f2bf(b.w);
    ((short8*)out)[t] = r;
}

// ---------------------------------------------------------------------------
// W[K][N] fp32 -> Wt[N][K] bf16, 32x32 LDS tiles
// ---------------------------------------------------------------------------
__global__ __launch_bounds__(256) void tr_bf16_kernel(
    const float* __restrict__ in, short* __restrict__ out, int K, int N)
{
    __shared__ float T[32][33];
    int n0 = blockIdx.x * 32, k0 = blockIdx.y * 32;
    int tx = threadIdx.x & 31, ty = threadIdx.x >> 5;
#pragma unroll
    for (int i = 0; i < 4; ++i)
        T[ty + i * 8][tx] = in[(size_t)(k0 + ty + i * 8) * N + n0 + tx];
    __syncthreads();
#pragma unroll
    for (int i = 0; i < 4; ++i)
        out[(size_t)(n0 + ty + i * 8) * K + k0 + tx] = f2bf(T[tx][ty + i * 8]);
}

// ---------------------------------------------------------------------------
// Merged QKV GEMM: [M,3072] = xb[M,2048] @ Wt[3072,2048]^T (+bias).
// n<2048 -> qb8 (b,s,h,hd); n<2560 -> kb8 (b,s,g,hd); else vt8 TRANSPOSED
// (b,g,dv,s) so attention can stage V^T with plain vector loads.
// ---------------------------------------------------------------------------
__global__ __launch_bounds__(256) void gemm_qkv(
    const short* __restrict__ A, const short* __restrict__ Bt,
    const float* __restrict__ bq, const float* __restrict__ bk,
    const float* __restrict__ bv, short* __restrict__ qout,
    short* __restrict__ kout, short* __restrict__ vout, int M, int N, int K)
{
    __shared__ short As[128 * 32];
    __shared__ short Bs[128 * 32];
    const int tid = threadIdx.x;
    const int w = tid >> 6, l15 = tid & 15, quad = (tid & 63) >> 4;
    const int wm = w >> 1, wn = w & 1;
    const int m0 = blockIdx.y * 128, n0 = blockIdx.x * 128;

    floatx4 acc[4][4];
#pragma unroll
    for (int i = 0; i < 4; ++i)
#pragma unroll
        for (int j = 0; j < 4; ++j) acc[i][j] = (floatx4){0.f, 0.f, 0.f, 0.f};

    const int arow = tid >> 2, akc = tid & 3;
    const short* Ag0 = A + (size_t)(m0 + arow) * K + akc * 8;
    const short* Ag1 = A + (size_t)(m0 + 64 + arow) * K + akc * 8;
    const short* Bg0 = Bt + (size_t)(n0 + arow) * K + akc * 8;
    const short* Bg1 = Bt + (size_t)(n0 + 64 + arow) * K + akc * 8;
    short* AsW0 = As + (w * 64) * 8;
    short* AsW1 = As + (256 + w * 64) * 8;
    short* BsW0 = Bs + (w * 64) * 8;
    short* BsW1 = Bs + (256 + w * 64) * 8;

    for (int k0 = 0; k0 < K; k0 += 32) {
        GLL16(Ag0 + k0, AsW0);
        GLL16(Ag1 + k0, AsW1);
        GLL16(Bg0 + k0, BsW0);
        GLL16(Bg1 + k0, BsW1);
        __syncthreads();
        short8 af[4], bfr[4];
#pragma unroll
        for (int mt = 0; mt < 4; ++mt)
            af[mt] = *(const short8*)(As + (wm * 64 + mt * 16 + l15) * 32 + quad * 8);
#pragma unroll
        for (int nt = 0; nt < 4; ++nt)
            bfr[nt] = *(const short8*)(Bs + (wn * 64 + nt * 16 + l15) * 32 + quad * 8);
#pragma unroll
        for (int mt = 0; mt < 4; ++mt)
#pragma unroll
            for (int nt = 0; nt < 4; ++nt)
                acc[mt][nt] = __builtin_amdgcn_mfma_f32_16x16x32_bf16(
                    af[mt], bfr[nt], acc[mt][nt], 0, 0, 0);
        __syncthreads();
    }

#pragma unroll
    for (int nt = 0; nt < 4; ++nt) {
        int gcol = n0 + wn * 64 + nt * 16 + l15;
        float bvv = (gcol < 2048) ? bq[gcol]
                  : (gcol < 2560) ? bk[gcol - 2048] : bv[gcol - 2560];
#pragma unroll
        for (int mt = 0; mt < 4; ++mt) {
            int grow = m0 + wm * 64 + mt * 16 + quad * 4;
            floatx4 v = acc[mt][nt];
            if (n0 < 2048) {
#pragma unroll
                for (int r = 0; r < 4; ++r)
                    qout[(size_t)(grow + r) * 2048 + gcol] = f2bf(v[r] + bvv);
            } else if (n0 < 2560) {
                int c = gcol - 2048;
#pragma unroll
                for (int r = 0; r < 4; ++r)
                    kout[(size_t)(grow + r) * 512 + c] = f2bf(v[r] + bvv);
            } else {
                int c = gcol - 2560, gg = c >> 7, dv = c & 127;
                int bb = grow >> 11, s = grow & 2047;
                uint2 pk;
                pk.x = pkr(v[0] + bvv, v[1] + bvv);
                pk.y = pkr(v[2] + bvv, v[3] + bvv);
                *(uint2*)&vout[(((size_t)bb * G_ + gg) * HD_ + dv) * S_ + s] = pk;
            }
        }
    }
}

// ---------------------------------------------------------------------------
// bf16 MFMA GEMM (O-projection): C[M,N] fp32 = A[M,K] @ Bt[N,K]^T + bias
// ---------------------------------------------------------------------------
__global__ __launch_bounds__(256) void gemm_nt_f32(
    const short* __restrict__ A, const short* __restrict__ Bt,
    const float* __restrict__ bias, float* __restrict__ C,
    int M, int N, int K)
{
    __shared__ short As[128 * 32];
    __shared__ short Bs[128 * 32];
    const int tid = threadIdx.x;
    const int w = tid >> 6, l15 = tid & 15, quad = (tid & 63) >> 4;
    const int wm = w >> 1, wn = w & 1;
    const int m0 = blockIdx.y * 128, n0 = blockIdx.x * 128;

    floatx4 acc[4][4];
#pragma unroll
    for (int i = 0; i < 4; ++i)
#pragma unroll
        for (int j = 0; j < 4; ++j) acc[i][j] = (floatx4){0.f, 0.f, 0.f, 0.f};

    const int arow = tid >> 2, akc = tid & 3;
    const short* Ag0 = A + (size_t)(m0 + arow) * K + akc * 8;
    const short* Ag1 = A + (size_t)(m0 + 64 + arow) * K + akc * 8;
    const short* Bg0 = Bt + (size_t)(n0 + arow) * K + akc * 8;
    const short* Bg1 = Bt + (size_t)(n0 + 64 + arow) * K + akc * 8;
    short* AsW0 = As + (w * 64) * 8;
    short* AsW1 = As + (256 + w * 64) * 8;
    short* BsW0 = Bs + (w * 64) * 8;
    short* BsW1 = Bs + (256 + w * 64) * 8;

    for (int k0 = 0; k0 < K; k0 += 32) {
        GLL16(Ag0 + k0, AsW0);
        GLL16(Ag1 + k0, AsW1);
        GLL16(Bg0 + k0, BsW0);
        GLL16(Bg1 + k0, BsW1);
        __syncthreads();
        short8 af[4], bfr[4];
#pragma unroll
        for (int mt = 0; mt < 4; ++mt)
            af[mt] = *(const short8*)(As + (wm * 64 + mt * 16 + l15) * 32 + quad * 8);
#pragma unroll
        for (int nt = 0; nt < 4; ++nt)
            bfr[nt] = *(const short8*)(Bs + (wn * 64 + nt * 16 + l15) * 32 + quad * 8);
#pragma unroll
        for (int mt = 0; mt < 4; ++mt)
#pragma unroll
            for (int nt = 0; nt < 4; ++nt)
                acc[mt][nt] = __builtin_amdgcn_mfma_f32_16x16x32_bf16(
                    af[mt], bfr[nt], acc[mt][nt], 0, 0, 0);
        __syncthreads();
    }

#pragma unroll
    for (int nt = 0; nt < 4; ++nt) {
        int gcol = n0 + wn * 64 + nt * 16 + l15;
        float bvv = bias[gcol];
#pragma unroll
        for (int mt = 0; mt < 4; ++mt) {
            int grow = m0 + wm * 64 + mt * 16 + quad * 4;
            floatx4 v = acc[mt][nt];
#pragma unroll
            for (int r = 0; r < 4; ++r)
                C[(size_t)(grow + r) * N + gcol] = v[r] + bvv;
        }
    }
}

// ---------------------------------------------------------------------------
// RoPE in-place on bf16 (B,S,nh,HD); fp32 trig (err 1e-4 << bf16 ulp)
// ---------------------------------------------------------------------------
__global__ void rope_bf16_kernel(short* __restrict__ p, int nh, float scale,
                                 int total)
{
    int gid = blockIdx.x * 256 + threadIdx.x;
    if (gid >= total) return;
    int i = gid & 63;
    int rest = gid >> 6;
    int head = rest % nh;
    int rest2 = rest / nh;
    int s = rest2 & (S_ - 1);
    int b = rest2 >> 11;
    size_t base = (((size_t)b * S_ + s) * nh + head) * HD_;
    float inv = __expf((float)i * -0.14391156509f);   // ln(1e4)/64
    float ang = (float)s * inv;
    float sn, cs;
    sincosf(ang, &sn, &cs);
    float t1 = b2f(p[base + i]), t2 = b2f(p[base + 64 + i]);
    p[base + i]      = f2bf((t1 * cs - t2 * sn) * scale);
    p[base + 64 + i] = f2bf((t2 * cs + t1 * sn) * scale);
}

// ---------------------------------------------------------------------------
// MFMA flash attention v4: BARRIER-FREE, direct global->register K/V frags.
// Diagnosis: v2/v3 were latency-bound (MfmaUtil 8%, VALUBusy 17%, HBM 4%,
// Occupancy ~6% -- nothing saturated). The shared K/V LDS staging forced
// (a) 50KB LDS -> only 3 blocks/CU, (b) 2-3 barriers per K-tile locking all
// 4 waves into the same serial chain. Every wave consumes the WHOLE K/V tile
// anyway, and the xor staging swizzle cancels against the read swizzle
// (global chunk = c*4+quad exactly), so fragments can be loaded straight
// from global memory into VGPRs:
//   - zero barriers in the main loop (waves free-run; cross-wave overlap)
//   - LDS 51.2KB -> 18.4KB (P only) -> 8 blocks/CU LDS-cap, ~7 waves/SIMD
//   - per-step LDS ops 36 -> 12 (P round-trip only, per-wave private)
// Cost: 4x K/V read duplication (served by L1/L2; ~2.2GB total, far under
// the 34.5 TB/s L2 ceiling). Wave-loads coalesce to 16 cache lines each.
// Block = 128 q-rows of one (b,h); wave = 32 q-rows; K-tile = 64 keys.
// S^T = K.Q^T (lane-local softmax); O^T = V^T.P^T; output in-place into qb.
// ---------------------------------------------------------------------------
#define PPITCH 72   // shorts; 144B = 16B-aligned, 4-bank stride -> 2-way

__global__ __launch_bounds__(256, 5) void attn_mfma2(
    short* __restrict__ qb, const short* __restrict__ kb,
    const short* __restrict__ vt)
{
    __shared__ short Ps[4][32 * PPITCH];   // per-wave P as [q][key]

    const int tid = threadIdx.x;
    const int w = tid >> 6, lane = tid & 63, l15 = lane & 15, quad = lane >> 4;
    const int qi = 15 - (int)blockIdx.x;          // heavy blocks first
    const int q0 = qi * 128;
    const int bh = blockIdx.y, b = bh >> 4, h = bh & 15, g = h >> 2;

    // Q fragments: rows q0 + w*32 + qs*16 + l15, d = quad*8 + 32c
    const short* qp = qb + ((((size_t)b * S_) + q0 + w * 32 + l15) * H_ + h) * HD_
                      + quad * 8;
    short8 qf[2][4];
#pragma unroll
    for (int qs = 0; qs < 2; ++qs)
#pragma unroll
        for (int c = 0; c < 4; ++c)
            qf[qs][c] = *(const short8*)(qp + qs * 16 * (H_ * HD_) + c * 32);

    floatx4 ot[2][8];
#pragma unroll
    for (int qs = 0; qs < 2; ++qs)
#pragma unroll
        for (int s = 0; s < 8; ++s) ot[qs][s] = (floatx4){0.f, 0.f, 0.f, 0.f};
    float m_i[2] = {-1e30f, -1e30f}, l_i[2] = {0.f, 0.f};

    // Direct global fragment bases (swizzle-free: LDS xor staging cancelled
    // against the read xor; global chunk index is plain c*4+quad).
    // K frag (c,ks): key = kt*64 + 16*ks + l15, d = c*32 + quad*8
    const short* kfp = kb + (((size_t)b * S_ + l15) * G_ + g) * HD_ + quad * 8;
    // V frag (s,kc): dv = 16*s + l15, key-chunk = kt*64 + kc*32 + quad*8
    const short* vfp = vt + (((size_t)(b * G_ + g)) * HD_ + l15) * (size_t)S_
                       + quad * 8;
    short* pw = Ps[w];

    const int nkt = 2 * (qi + 1);
    for (int kt = 0; kt < nkt; ++kt) {
        // ---- K-tile fragments straight from global (16 x dwordx4)
        const short* kA = kfp + (size_t)(kt * 64) * (G_ * HD_);
        short8 kf[4][4];
#pragma unroll
        for (int c = 0; c < 4; ++c)
#pragma unroll
            for (int ks = 0; ks < 4; ++ks)
                kf[c][ks] = *(const short8*)(kA +
                    (size_t)(16 * ks) * (G_ * HD_) + c * 32);

        // ---- S^T tiles: sa[qs][ksub], row = key = ksub*16+quad*4+r, col = q = l15
        floatx4 sa[2][4];
#pragma unroll
        for (int qs = 0; qs < 2; ++qs)
#pragma unroll
            for (int ks = 0; ks < 4; ++ks) sa[qs][ks] = (floatx4){0.f, 0.f, 0.f, 0.f};
#pragma unroll
        for (int c = 0; c < 4; ++c)
#pragma unroll
            for (int ks = 0; ks < 4; ++ks) {
                sa[0][ks] = __builtin_amdgcn_mfma_f32_16x16x32_bf16(
                    kf[c][ks], qf[0][c], sa[0][ks], 0, 0, 0);
                sa[1][ks] = __builtin_amdgcn_mfma_f32_16x16x32_bf16(
                    kf[c][ks], qf[1][c], sa[1][ks], 0, 0, 0);
            }

        const int kbase = kt * 64;
#pragma unroll
        for (int qs = 0; qs < 2; ++qs) {
            const int qrow = q0 + w * 32 + qs * 16 + l15;
            // causal mask (only near diagonal; uniform per qs)
            if (kbase + 63 > q0 + w * 32 + qs * 16) {
#pragma unroll
                for (int ks = 0; ks < 4; ++ks)
#pragma unroll
                    for (int r = 0; r < 4; ++r)
                        if (kbase + ks * 16 + quad * 4 + r > qrow)
                            sa[qs][ks][r] = -1e30f;
            }
            // ---- lane-local online softmax over this lane's 16 keys + 2 shfl
            float mx = -1e30f;
#pragma unroll
            for (int ks = 0; ks < 4; ++ks)
#pragma unroll
                for (int r = 0; r < 4; ++r) mx = fmaxf(mx, sa[qs][ks][r]);
            mx = fmaxf(mx, __shfl_xor(mx, 16));
            mx = fmaxf(mx, __shfl_xor(mx, 32));
            float mo = m_i[qs];
            // defer-max: only rescale when some lane's max outgrew by >8
            if (!__all(mx - mo <= 8.0f)) {
                float mn = fmaxf(mo, mx);
                float al = __expf(mo - mn);
                m_i[qs] = mn;
                l_i[qs] *= al;
#pragma unroll
                for (int s = 0; s < 8; ++s) {
                    floatx4 o = ot[qs][s];
                    o[0] *= al; o[1] *= al; o[2] *= al; o[3] *= al;
                    ot[qs][s] = o;
                }
                mo = mn;
            }
            float s0 = 0.f, s1 = 0.f, s2 = 0.f, s3 = 0.f;
#pragma unroll
            for (int ks = 0; ks < 4; ++ks) {
                float p0 = __expf(sa[qs][ks][0] - mo);
                float p1 = __expf(sa[qs][ks][1] - mo);
                float p2 = __expf(sa[qs][ks][2] - mo);
                float p3 = __expf(sa[qs][ks][3] - mo);
                sa[qs][ks][0] = p0; sa[qs][ks][1] = p1;
                sa[qs][ks][2] = p2; sa[qs][ks][3] = p3;
                s0 += p0; s1 += p1; s2 += p2; s3 += p3;
            }
            float sum = (s0 + s1) + (s2 + s3);
            sum += __shfl_xor(sum, 16);
            sum += __shfl_xor(sum, 32);
            l_i[qs] += sum;
            // ---- P -> per-wave LDS as [q][key] (b64 writes; wave-private,
            // in-order LDS pipe makes this barrier-free)
            short* pr = pw + (qs * 16 + l15) * PPITCH;
#pragma unroll
            for (int ks = 0; ks < 4; ++ks) {
                uint2 pkv;
                pkv.x = pk2(sa[qs][ks][0], sa[qs][ks][1]);
                pkv.y = pk2(sa[qs][ks][2], sa[qs][ks][3]);
                *(uint2*)(pr + ks * 16 + quad * 4) = pkv;
            }
        }

        // ---- O^T += V^T . P^T  (V frags straight from global; shared
        //      across both q-subtiles)
        const short* vA = vfp + kt * 64;
#pragma unroll
        for (int kc = 0; kc < 2; ++kc) {
            short8 pf0 = *(const short8*)(pw + l15 * PPITCH + kc * 32 + quad * 8);
            short8 pf1 = *(const short8*)(pw + (16 + l15) * PPITCH + kc * 32 + quad * 8);
#pragma unroll
            for (int s = 0; s < 8; ++s) {
                short8 vf = *(const short8*)(vA + (size_t)(16 * s) * S_ + kc * 32);
                ot[0][s] = __builtin_amdgcn_mfma_f32_16x16x32_bf16(
                    vf, pf0, ot[0][s], 0, 0, 0);
                ot[1][s] = __builtin_amdgcn_mfma_f32_16x16x32_bf16(
                    vf, pf1, ot[1][s], 0, 0, 0);
            }
        }
    }

    // ---- epilogue: normalize (lane-local l), write bf16 in-place
#pragma unroll
    for (int qs = 0; qs < 2; ++qs) {
        float inv = 1.f / l_i[qs];
        size_t base = ((((size_t)b * S_) + q0 + w * 32 + qs * 16 + l15) * H_ + h)
                      * HD_;
#pragma unroll
        for (int s = 0; s < 8; ++s) {
            uint2 pkv;
            pkv.x = pkr(ot[qs][s][0] * inv, ot[qs][s][1] * inv);
            pkv.y = pkr(ot[qs][s][2] * inv, ot[qs][s][3] * inv);
            *(uint2*)&qb[base + s * 16 + quad * 4] = pkv;
        }
    }
}

// ---------------------------------------------------------------------------
extern "C" void kernel_launch(void* const* d_in, const int* in_sizes, int n_in,
                              void* d_out, int out_size, void* d_ws, size_t ws_size,
                              hipStream_t stream)
{
    const float* x  = (const float*)d_in[0];
    const float* Wq = (const float*)d_in[1];
    const float* bq = (const float*)d_in[2];
    const float* Wk = (const float*)d_in[3];
    const float* bk = (const float*)d_in[4];
    const float* Wv = (const float*)d_in[5];
    const float* bv = (const float*)d_in[6];
    const float* Wo = (const float*)d_in[7];
    const float* bo = (const float*)d_in[8];
    float* out = (float*)d_out;

    // ws layout (bf16 elements); total 96.5 MB
    short* xb  = (short*)d_ws;        // 16,777,216
    short* Wt  = xb + 16777216;       // 3072*2048 = 6,291,456 (reused for Wo^T)
    short* qb8 = Wt + 6291456;        // 16,777,216 (q -> attn out, in-place)
    short* kb8 = qb8 + 16777216;      // 4,194,304
    short* vt8 = kb8 + 4194304;       // 4,194,304  V^T (b,g,dv,s)

    const int M = B_ * S_;
    dim3 blk(256);

    cvt_bf16_kernel<<<8192, blk, 0, stream>>>(x, xb, 16777216 / 8);
    tr_bf16_kernel<<<dim3(64, 64), blk, 0, stream>>>(Wq, Wt, 2048, 2048);
    tr_bf16_kernel<<<dim3(16, 64), blk, 0, stream>>>(Wk, Wt + (size_t)2048 * 2048, 2048, 512);
    tr_bf16_kernel<<<dim3(16, 64), blk, 0, stream>>>(Wv, Wt + (size_t)2560 * 2048, 2048, 512);

    gemm_qkv<<<dim3(24, 64), blk, 0, stream>>>(xb, Wt, bq, bk, bv,
                                               qb8, kb8, vt8, M, 3072, 2048);

    // Wt slot free now -> Wo^T (stream-ordered)
    tr_bf16_kernel<<<dim3(64, 64), blk, 0, stream>>>(Wo, Wt, 2048, 2048);

    const float qscale = 0.08838834764831845f;   // 1/sqrt(128)
    rope_bf16_kernel<<<32768, blk, 0, stream>>>(qb8, H_, qscale, M * H_ * 64);
    rope_bf16_kernel<<<8192,  blk, 0, stream>>>(kb8, G_, 1.0f,   M * G_ * 64);

    attn_mfma2<<<dim3(16, 64), blk, 0, stream>>>(qb8, kb8, vt8);

    gemm_nt_f32<<<dim3(16, 64), blk, 0, stream>>>(qb8, Wt, bo, out, M, 2048, 2048);
}

// Round 3
// 842.946 us; speedup vs baseline: 1.6008x; 1.6008x over previous
//
#include <hip/hip_runtime.h>
#include <hip/hip_bf16.h>
#include <math.h>

#define B_  4
#define S_  2048
#define D_  2048
#define H_  16
#define G_  4
#define HD_ 128

typedef __attribute__((ext_vector_type(8))) short short8;
typedef __attribute__((ext_vector_type(4))) float floatx4;

__device__ __forceinline__ short f2bf(float f) {
    unsigned u = __float_as_uint(f);
    unsigned r = (u + 0x7fff + ((u >> 16) & 1)) >> 16;
    return (short)r;
}
__device__ __forceinline__ float b2f(short s) {
    return __uint_as_float(((unsigned)(unsigned short)s) << 16);
}
// pack two floats to bf16x2, round-half-up (cheap; used for P)
__device__ __forceinline__ unsigned pk2(float a, float b) {
    unsigned ua = (__float_as_uint(a) + 0x8000u) >> 16;
    unsigned ub = (__float_as_uint(b) + 0x8000u) & 0xffff0000u;
    return ua | ub;
}
// pack two floats to bf16x2, RNE (outputs)
__device__ __forceinline__ unsigned pkr(float a, float b) {
    return (unsigned)(unsigned short)f2bf(a) |
           ((unsigned)(unsigned short)f2bf(b) << 16);
}

#define GLL16(gp, lp) __builtin_amdgcn_global_load_lds( \
    (const __attribute__((address_space(1))) void*)(gp), \
    (__attribute__((address_space(3))) void*)(lp), 16, 0, 0)

// ---------------------------------------------------------------------------
// fp32 -> bf16 convert (8 elems/thread)
// ---------------------------------------------------------------------------
__global__ void cvt_bf16_kernel(const float* __restrict__ in,
                                short* __restrict__ out, int n8)
{
    int t = blockIdx.x * 256 + threadIdx.x;
    if (t >= n8) return;
    const float4* p = (const float4*)in + (size_t)t * 2;
    float4 a = p[0], b = p[1];
    short8 r;
    r[0] = f2bf(a.x); r[1] = f2bf(a.y); r[2] = f2bf(a.z); r[3] = f2bf(a.w);
    r[4] = f2bf(b.x); r[5] = f2bf(b.y); r[6] = f2bf(b.z); r[7] = f2bf(b.w);
    ((short8*)out)[t] = r;
}

// ---------------------------------------------------------------------------
// W[K][N] fp32 -> Wt[N][K] bf16, 32x32 LDS tiles
// ---------------------------------------------------------------------------
__global__ __launch_bounds__(256) void tr_bf16_kernel(
    const float* __restrict__ in, short* __restrict__ out, int K, int N)
{
    __shared__ float T[32][33];
    int n0 = blockIdx.x * 32, k0 = blockIdx.y * 32;
    int tx = threadIdx.x & 31, ty = threadIdx.x >> 5;
#pragma unroll
    for (int i = 0; i < 4; ++i)
        T[ty + i * 8][tx] = in[(size_t)(k0 + ty + i * 8) * N + n0 + tx];
    __syncthreads();
#pragma unroll
    for (int i = 0; i < 4; ++i)
        out[(size_t)(n0 + ty + i * 8) * K + k0 + tx] = f2bf(T[tx][ty + i * 8]);
}

// ---------------------------------------------------------------------------
// Merged QKV GEMM: [M,3072] = xb[M,2048] @ Wt[3072,2048]^T (+bias).
// n<2048 -> qb8 (b,s,h,hd); n<2560 -> kb8 (b,s,g,hd); else vt8 TRANSPOSED
// (b,g,dv,s) so attention can stage V^T with plain vector loads.
// ---------------------------------------------------------------------------
__global__ __launch_bounds__(256) void gemm_qkv(
    const short* __restrict__ A, const short* __restrict__ Bt,
    const float* __restrict__ bq, const float* __restrict__ bk,
    const float* __restrict__ bv, short* __restrict__ qout,
    short* __restrict__ kout, short* __restrict__ vout, int M, int N, int K)
{
    __shared__ short As[128 * 32];
    __shared__ short Bs[128 * 32];
    const int tid = threadIdx.x;
    const int w = tid >> 6, l15 = tid & 15, quad = (tid & 63) >> 4;
    const int wm = w >> 1, wn = w & 1;
    const int m0 = blockIdx.y * 128, n0 = blockIdx.x * 128;

    floatx4 acc[4][4];
#pragma unroll
    for (int i = 0; i < 4; ++i)
#pragma unroll
        for (int j = 0; j < 4; ++j) acc[i][j] = (floatx4){0.f, 0.f, 0.f, 0.f};

    const int arow = tid >> 2, akc = tid & 3;
    const short* Ag0 = A + (size_t)(m0 + arow) * K + akc * 8;
    const short* Ag1 = A + (size_t)(m0 + 64 + arow) * K + akc * 8;
    const short* Bg0 = Bt + (size_t)(n0 + arow) * K + akc * 8;
    const short* Bg1 = Bt + (size_t)(n0 + 64 + arow) * K + akc * 8;
    short* AsW0 = As + (w * 64) * 8;
    short* AsW1 = As + (256 + w * 64) * 8;
    short* BsW0 = Bs + (w * 64) * 8;
    short* BsW1 = Bs + (256 + w * 64) * 8;

    for (int k0 = 0; k0 < K; k0 += 32) {
        GLL16(Ag0 + k0, AsW0);
        GLL16(Ag1 + k0, AsW1);
        GLL16(Bg0 + k0, BsW0);
        GLL16(Bg1 + k0, BsW1);
        __syncthreads();
        short8 af[4], bfr[4];
#pragma unroll
        for (int mt = 0; mt < 4; ++mt)
            af[mt] = *(const short8*)(As + (wm * 64 + mt * 16 + l15) * 32 + quad * 8);
#pragma unroll
        for (int nt = 0; nt < 4; ++nt)
            bfr[nt] = *(const short8*)(Bs + (wn * 64 + nt * 16 + l15) * 32 + quad * 8);
#pragma unroll
        for (int mt = 0; mt < 4; ++mt)
#pragma unroll
            for (int nt = 0; nt < 4; ++nt)
                acc[mt][nt] = __builtin_amdgcn_mfma_f32_16x16x32_bf16(
                    af[mt], bfr[nt], acc[mt][nt], 0, 0, 0);
        __syncthreads();
    }

#pragma unroll
    for (int nt = 0; nt < 4; ++nt) {
        int gcol = n0 + wn * 64 + nt * 16 + l15;
        float bvv = (gcol < 2048) ? bq[gcol]
                  : (gcol < 2560) ? bk[gcol - 2048] : bv[gcol - 2560];
#pragma unroll
        for (int mt = 0; mt < 4; ++mt) {
            int grow = m0 + wm * 64 + mt * 16 + quad * 4;
            floatx4 v = acc[mt][nt];
            if (n0 < 2048) {
#pragma unroll
                for (int r = 0; r < 4; ++r)
                    qout[(size_t)(grow + r) * 2048 + gcol] = f2bf(v[r] + bvv);
            } else if (n0 < 2560) {
                int c = gcol - 2048;
#pragma unroll
                for (int r = 0; r < 4; ++r)
                    kout[(size_t)(grow + r) * 512 + c] = f2bf(v[r] + bvv);
            } else {
                int c = gcol - 2560, gg = c >> 7, dv = c & 127;
                int bb = grow >> 11, s = grow & 2047;
                uint2 pk;
                pk.x = pkr(v[0] + bvv, v[1] + bvv);
                pk.y = pkr(v[2] + bvv, v[3] + bvv);
                *(uint2*)&vout[(((size_t)bb * G_ + gg) * HD_ + dv) * S_ + s] = pk;
            }
        }
    }
}

// ---------------------------------------------------------------------------
// bf16 MFMA GEMM (O-projection): C[M,N] fp32 = A[M,K] @ Bt[N,K]^T + bias
// ---------------------------------------------------------------------------
__global__ __launch_bounds__(256) void gemm_nt_f32(
    const short* __restrict__ A, const short* __restrict__ Bt,
    const float* __restrict__ bias, float* __restrict__ C,
    int M, int N, int K)
{
    __shared__ short As[128 * 32];
    __shared__ short Bs[128 * 32];
    const int tid = threadIdx.x;
    const int w = tid >> 6, l15 = tid & 15, quad = (tid & 63) >> 4;
    const int wm = w >> 1, wn = w & 1;
    const int m0 = blockIdx.y * 128, n0 = blockIdx.x * 128;

    floatx4 acc[4][4];
#pragma unroll
    for (int i = 0; i < 4; ++i)
#pragma unroll
        for (int j = 0; j < 4; ++j) acc[i][j] = (floatx4){0.f, 0.f, 0.f, 0.f};

    const int arow = tid >> 2, akc = tid & 3;
    const short* Ag0 = A + (size_t)(m0 + arow) * K + akc * 8;
    const short* Ag1 = A + (size_t)(m0 + 64 + arow) * K + akc * 8;
    const short* Bg0 = Bt + (size_t)(n0 + arow) * K + akc * 8;
    const short* Bg1 = Bt + (size_t)(n0 + 64 + arow) * K + akc * 8;
    short* AsW0 = As + (w * 64) * 8;
    short* AsW1 = As + (256 + w * 64) * 8;
    short* BsW0 = Bs + (w * 64) * 8;
    short* BsW1 = Bs + (256 + w * 64) * 8;

    for (int k0 = 0; k0 < K; k0 += 32) {
        GLL16(Ag0 + k0, AsW0);
        GLL16(Ag1 + k0, AsW1);
        GLL16(Bg0 + k0, BsW0);
        GLL16(Bg1 + k0, BsW1);
        __syncthreads();
        short8 af[4], bfr[4];
#pragma unroll
        for (int mt = 0; mt < 4; ++mt)
            af[mt] = *(const short8*)(As + (wm * 64 + mt * 16 + l15) * 32 + quad * 8);
#pragma unroll
        for (int nt = 0; nt < 4; ++nt)
            bfr[nt] = *(const short8*)(Bs + (wn * 64 + nt * 16 + l15) * 32 + quad * 8);
#pragma unroll
        for (int mt = 0; mt < 4; ++mt)
#pragma unroll
            for (int nt = 0; nt < 4; ++nt)
                acc[mt][nt] = __builtin_amdgcn_mfma_f32_16x16x32_bf16(
                    af[mt], bfr[nt], acc[mt][nt], 0, 0, 0);
        __syncthreads();
    }

#pragma unroll
    for (int nt = 0; nt < 4; ++nt) {
        int gcol = n0 + wn * 64 + nt * 16 + l15;
        float bvv = bias[gcol];
#pragma unroll
        for (int mt = 0; mt < 4; ++mt) {
            int grow = m0 + wm * 64 + mt * 16 + quad * 4;
            floatx4 v = acc[mt][nt];
#pragma unroll
            for (int r = 0; r < 4; ++r)
                C[(size_t)(grow + r) * N + gcol] = v[r] + bvv;
        }
    }
}

// ---------------------------------------------------------------------------
// RoPE in-place on bf16 (B,S,nh,HD); fp32 trig (err 1e-4 << bf16 ulp)
// ---------------------------------------------------------------------------
__global__ void rope_bf16_kernel(short* __restrict__ p, int nh, float scale,
                                 int total)
{
    int gid = blockIdx.x * 256 + threadIdx.x;
    if (gid >= total) return;
    int i = gid & 63;
    int rest = gid >> 6;
    int head = rest % nh;
    int rest2 = rest / nh;
    int s = rest2 & (S_ - 1);
    int b = rest2 >> 11;
    size_t base = (((size_t)b * S_ + s) * nh + head) * HD_;
    float inv = __expf((float)i * -0.14391156509f);   // ln(1e4)/64
    float ang = (float)s * inv;
    float sn, cs;
    sincosf(ang, &sn, &cs);
    float t1 = b2f(p[base + i]), t2 = b2f(p[base + 64 + i]);
    p[base + i]      = f2bf((t1 * cs - t2 * sn) * scale);
    p[base + 64 + i] = f2bf((t2 * cs + t1 * sn) * scale);
}

// ---------------------------------------------------------------------------
// MFMA flash attention v5: 1-WAVE blocks, barrier-free, direct global->VGPR.
// R2 post-mortem: the direct-global design was correct (absmax unchanged) but
// __launch_bounds__(256,5) capped the allocator at 48 VGPRs -> the ~210-VGPR
// working set spilled to scratch (WRITE_SIZE 32MB->1.2GB, FETCH +0.9GB).
// Fix: __launch_bounds__(64, 2) -> 256-VGPR budget, no spill.
// Block = ONE wave = 32 q-rows of one (b,h). No barriers anywhere; waves
// free-run and hide each other's latency. Grid (64,64) = 4096 blocks (4x v2)
// -> residency is VGPR-capped (~2 waves/SIMD, 8 blocks/CU), not LDS-capped.
// P round-trip stays in a wave-private 4.6KB LDS buffer (no sync needed).
// Per-wave nkt = qw/2+1 (no longer rounded up to the 128-row block).
// K/V frags straight from global: L1/L2/L3 serve the 4x duplication (R2
// showed 2.3 TB/s sustained; unique data 48MB << 256MB L3).
// S^T = K.Q^T (lane-local softmax); O^T = V^T.P^T; output in-place into qb.
// ---------------------------------------------------------------------------
#define PPITCH 72   // shorts; 144B = 16B-aligned, 4-bank stride -> 2-way

__global__ __launch_bounds__(64, 2) void attn_mfma2(
    short* __restrict__ qb, const short* __restrict__ kb,
    const short* __restrict__ vt)
{
    __shared__ short Ps[32 * PPITCH];   // wave-private P as [q][key]

    const int lane = threadIdx.x, l15 = lane & 15, quad = lane >> 4;
    const int qw = 63 - (int)blockIdx.x;          // heavy waves first
    const int qr0 = qw * 32;                      // first q-row of this wave
    const int bh = blockIdx.y, b = bh >> 4, h = bh & 15, g = h >> 2;

    // Q fragments: rows qr0 + qs*16 + l15, d = quad*8 + 32c
    const short* qp = qb + ((((size_t)b * S_) + qr0 + l15) * H_ + h) * HD_
                      + quad * 8;
    short8 qf[2][4];
#pragma unroll
    for (int qs = 0; qs < 2; ++qs)
#pragma unroll
        for (int c = 0; c < 4; ++c)
            qf[qs][c] = *(const short8*)(qp + qs * 16 * (H_ * HD_) + c * 32);

    floatx4 ot[2][8];
#pragma unroll
    for (int qs = 0; qs < 2; ++qs)
#pragma unroll
        for (int s = 0; s < 8; ++s) ot[qs][s] = (floatx4){0.f, 0.f, 0.f, 0.f};
    float m_i[2] = {-1e30f, -1e30f}, l_i[2] = {0.f, 0.f};

    // Direct global fragment bases.
    // K frag (c,ks): key = kt*64 + 16*ks + l15, d = c*32 + quad*8
    const short* kfp = kb + (((size_t)b * S_ + l15) * G_ + g) * HD_ + quad * 8;
    // V frag (s,kc): dv = 16*s + l15, key-chunk = kt*64 + kc*32 + quad*8
    const short* vfp = vt + (((size_t)(b * G_ + g)) * HD_ + l15) * (size_t)S_
                       + quad * 8;
    short* pw = Ps;

    const int nkt = (qw >> 1) + 1;
    for (int kt = 0; kt < nkt; ++kt) {
        // ---- K-tile fragments straight from global (16 x dwordx4)
        const short* kA = kfp + (size_t)(kt * 64) * (G_ * HD_);
        short8 kf[4][4];
#pragma unroll
        for (int c = 0; c < 4; ++c)
#pragma unroll
            for (int ks = 0; ks < 4; ++ks)
                kf[c][ks] = *(const short8*)(kA +
                    (size_t)(16 * ks) * (G_ * HD_) + c * 32);

        // ---- S^T tiles: sa[qs][ksub], row = key = ksub*16+quad*4+r, col = q = l15
        floatx4 sa[2][4];
#pragma unroll
        for (int qs = 0; qs < 2; ++qs)
#pragma unroll
            for (int ks = 0; ks < 4; ++ks) sa[qs][ks] = (floatx4){0.f, 0.f, 0.f, 0.f};
#pragma unroll
        for (int c = 0; c < 4; ++c)
#pragma unroll
            for (int ks = 0; ks < 4; ++ks) {
                sa[0][ks] = __builtin_amdgcn_mfma_f32_16x16x32_bf16(
                    kf[c][ks], qf[0][c], sa[0][ks], 0, 0, 0);
                sa[1][ks] = __builtin_amdgcn_mfma_f32_16x16x32_bf16(
                    kf[c][ks], qf[1][c], sa[1][ks], 0, 0, 0);
            }

        const int kbase = kt * 64;
#pragma unroll
        for (int qs = 0; qs < 2; ++qs) {
            const int qrow = qr0 + qs * 16 + l15;
            // causal mask (only near diagonal; uniform per qs)
            if (kbase + 63 > qr0 + qs * 16) {
#pragma unroll
                for (int ks = 0; ks < 4; ++ks)
#pragma unroll
                    for (int r = 0; r < 4; ++r)
                        if (kbase + ks * 16 + quad * 4 + r > qrow)
                            sa[qs][ks][r] = -1e30f;
            }
            // ---- lane-local online softmax over this lane's 16 keys + 2 shfl
            float mx = -1e30f;
#pragma unroll
            for (int ks = 0; ks < 4; ++ks)
#pragma unroll
                for (int r = 0; r < 4; ++r) mx = fmaxf(mx, sa[qs][ks][r]);
            mx = fmaxf(mx, __shfl_xor(mx, 16));
            mx = fmaxf(mx, __shfl_xor(mx, 32));
            float mo = m_i[qs];
            // defer-max: only rescale when some lane's max outgrew by >8
            if (!__all(mx - mo <= 8.0f)) {
                float mn = fmaxf(mo, mx);
                float al = __expf(mo - mn);
                m_i[qs] = mn;
                l_i[qs] *= al;
#pragma unroll
                for (int s = 0; s < 8; ++s) {
                    floatx4 o = ot[qs][s];
                    o[0] *= al; o[1] *= al; o[2] *= al; o[3] *= al;
                    ot[qs][s] = o;
                }
                mo = mn;
            }
            float s0 = 0.f, s1 = 0.f, s2 = 0.f, s3 = 0.f;
#pragma unroll
            for (int ks = 0; ks < 4; ++ks) {
                float p0 = __expf(sa[qs][ks][0] - mo);
                float p1 = __expf(sa[qs][ks][1] - mo);
                float p2 = __expf(sa[qs][ks][2] - mo);
                float p3 = __expf(sa[qs][ks][3] - mo);
                sa[qs][ks][0] = p0; sa[qs][ks][1] = p1;
                sa[qs][ks][2] = p2; sa[qs][ks][3] = p3;
                s0 += p0; s1 += p1; s2 += p2; s3 += p3;
            }
            float sum = (s0 + s1) + (s2 + s3);
            sum += __shfl_xor(sum, 16);
            sum += __shfl_xor(sum, 32);
            l_i[qs] += sum;
            // ---- P -> wave-private LDS as [q][key] (b64 writes; no barrier:
            // same-wave LDS RAW handled by lgkmcnt)
            short* pr = pw + (qs * 16 + l15) * PPITCH;
#pragma unroll
            for (int ks = 0; ks < 4; ++ks) {
                uint2 pkv;
                pkv.x = pk2(sa[qs][ks][0], sa[qs][ks][1]);
                pkv.y = pk2(sa[qs][ks][2], sa[qs][ks][3]);
                *(uint2*)(pr + ks * 16 + quad * 4) = pkv;
            }
        }

        // ---- O^T += V^T . P^T  (V frags straight from global; shared
        //      across both q-subtiles)
        const short* vA = vfp + kt * 64;
#pragma unroll
        for (int kc = 0; kc < 2; ++kc) {
            short8 pf0 = *(const short8*)(pw + l15 * PPITCH + kc * 32 + quad * 8);
            short8 pf1 = *(const short8*)(pw + (16 + l15) * PPITCH + kc * 32 + quad * 8);
#pragma unroll
            for (int s = 0; s < 8; ++s) {
                short8 vf = *(const short8*)(vA + (size_t)(16 * s) * S_ + kc * 32);
                ot[0][s] = __builtin_amdgcn_mfma_f32_16x16x32_bf16(
                    vf, pf0, ot[0][s], 0, 0, 0);
                ot[1][s] = __builtin_amdgcn_mfma_f32_16x16x32_bf16(
                    vf, pf1, ot[1][s], 0, 0, 0);
            }
        }
    }

    // ---- epilogue: normalize (lane-local l), write bf16 in-place
#pragma unroll
    for (int qs = 0; qs < 2; ++qs) {
        float inv = 1.f / l_i[qs];
        size_t base = ((((size_t)b * S_) + qr0 + qs * 16 + l15) * H_ + h)
                      * HD_;
#pragma unroll
        for (int s = 0; s < 8; ++s) {
            uint2 pkv;
            pkv.x = pkr(ot[qs][s][0] * inv, ot[qs][s][1] * inv);
            pkv.y = pkr(ot[qs][s][2] * inv, ot[qs][s][3] * inv);
            *(uint2*)&qb[base + s * 16 + quad * 4] = pkv;
        }
    }
}

// ---------------------------------------------------------------------------
extern "C" void kernel_launch(void* const* d_in, const int* in_sizes, int n_in,
                              void* d_out, int out_size, void* d_ws, size_t ws_size,
                              hipStream_t stream)
{
    const float* x  = (const float*)d_in[0];
    const float* Wq = (const float*)d_in[1];
    const float* bq = (const float*)d_in[2];
    const float* Wk = (const float*)d_in[3];
    const float* bk = (const float*)d_in[4];
    const float* Wv = (const float*)d_in[5];
    const float* bv = (const float*)d_in[6];
    const float* Wo = (const float*)d_in[7];
    const float* bo = (const float*)d_in[8];
    float* out = (float*)d_out;

    // ws layout (bf16 elements); total 96.5 MB
    short* xb  = (short*)d_ws;        // 16,777,216
    short* Wt  = xb + 16777216;       // 3072*2048 = 6,291,456 (reused for Wo^T)
    short* qb8 = Wt + 6291456;        // 16,777,216 (q -> attn out, in-place)
    short* kb8 = qb8 + 16777216;      // 4,194,304
    short* vt8 = kb8 + 4194304;       // 4,194,304  V^T (b,g,dv,s)

    const int M = B_ * S_;
    dim3 blk(256);

    cvt_bf16_kernel<<<8192, blk, 0, stream>>>(x, xb, 16777216 / 8);
    tr_bf16_kernel<<<dim3(64, 64), blk, 0, stream>>>(Wq, Wt, 2048, 2048);
    tr_bf16_kernel<<<dim3(16, 64), blk, 0, stream>>>(Wk, Wt + (size_t)2048 * 2048, 2048, 512);
    tr_bf16_kernel<<<dim3(16, 64), blk, 0, stream>>>(Wv, Wt + (size_t)2560 * 2048, 2048, 512);

    gemm_qkv<<<dim3(24, 64), blk, 0, stream>>>(xb, Wt, bq, bk, bv,
                                               qb8, kb8, vt8, M, 3072, 2048);

    // Wt slot free now -> Wo^T (stream-ordered)
    tr_bf16_kernel<<<dim3(64, 64), blk, 0, stream>>>(Wo, Wt, 2048, 2048);

    const float qscale = 0.08838834764831845f;   // 1/sqrt(128)
    rope_bf16_kernel<<<32768, blk, 0, stream>>>(qb8, H_, qscale, M * H_ * 64);
    rope_bf16_kernel<<<8192,  blk, 0, stream>>>(kb8, G_, 1.0f,   M * G_ * 64);

    attn_mfma2<<<dim3(64, 64), dim3(64), 0, stream>>>(qb8, kb8, vt8);

    gemm_nt_f32<<<dim3(16, 64), blk, 0, stream>>>(qb8, Wt, bo, out, M, 2048, 2048);
}

// Round 4
// 636.602 us; speedup vs baseline: 2.1197x; 1.3241x over previous
//
#include <hip/hip_runtime.h>
#include <hip/hip_bf16.h>
#include <math.h>

#define B_  4
#define S_  2048
#define D_  2048
#define H_  16
#define G_  4
#define HD_ 128

typedef __attribute__((ext_vector_type(8))) short short8;
typedef __attribute__((ext_vector_type(4))) float floatx4;

__device__ __forceinline__ short f2bf(float f) {
    unsigned u = __float_as_uint(f);
    unsigned r = (u + 0x7fff + ((u >> 16) & 1)) >> 16;
    return (short)r;
}
__device__ __forceinline__ float b2f(short s) {
    return __uint_as_float(((unsigned)(unsigned short)s) << 16);
}
// pack two floats to bf16x2, round-half-up (cheap; used for P)
__device__ __forceinline__ unsigned pk2(float a, float b) {
    unsigned ua = (__float_as_uint(a) + 0x8000u) >> 16;
    unsigned ub = (__float_as_uint(b) + 0x8000u) & 0xffff0000u;
    return ua | ub;
}
// pack two floats to bf16x2, RNE (outputs)
__device__ __forceinline__ unsigned pkr(float a, float b) {
    return (unsigned)(unsigned short)f2bf(a) |
           ((unsigned)(unsigned short)f2bf(b) << 16);
}

#define GLL16(gp, lp) __builtin_amdgcn_global_load_lds( \
    (const __attribute__((address_space(1))) void*)(gp), \
    (__attribute__((address_space(3))) void*)(lp), 16, 0, 0)

// ---------------------------------------------------------------------------
// fp32 -> bf16 convert (8 elems/thread)
// ---------------------------------------------------------------------------
__global__ void cvt_bf16_kernel(const float* __restrict__ in,
                                short* __restrict__ out, int n8)
{
    int t = blockIdx.x * 256 + threadIdx.x;
    if (t >= n8) return;
    const float4* p = (const float4*)in + (size_t)t * 2;
    float4 a = p[0], b = p[1];
    short8 r;
    r[0] = f2bf(a.x); r[1] = f2bf(a.y); r[2] = f2bf(a.z); r[3] = f2bf(a.w);
    r[4] = f2bf(b.x); r[5] = f2bf(b.y); r[6] = f2bf(b.z); r[7] = f2bf(b.w);
    ((short8*)out)[t] = r;
}

// ---------------------------------------------------------------------------
// W[K][N] fp32 -> Wt[N][K] bf16, 32x32 LDS tiles
// ---------------------------------------------------------------------------
__global__ __launch_bounds__(256) void tr_bf16_kernel(
    const float* __restrict__ in, short* __restrict__ out, int K, int N)
{
    __shared__ float T[32][33];
    int n0 = blockIdx.x * 32, k0 = blockIdx.y * 32;
    int tx = threadIdx.x & 31, ty = threadIdx.x >> 5;
#pragma unroll
    for (int i = 0; i < 4; ++i)
        T[ty + i * 8][tx] = in[(size_t)(k0 + ty + i * 8) * N + n0 + tx];
    __syncthreads();
#pragma unroll
    for (int i = 0; i < 4; ++i)
        out[(size_t)(n0 + ty + i * 8) * K + k0 + tx] = f2bf(T[tx][ty + i * 8]);
}

// ---------------------------------------------------------------------------
// Merged QKV GEMM: [M,3072] = xb[M,2048] @ Wt[3072,2048]^T (+bias).
// n<2048 -> qb8 (b,s,h,hd); n<2560 -> kb8 (b,s,g,hd); else vt8 TRANSPOSED
// (b,g,dv,s) so attention can stage V^T with plain vector loads.
// ---------------------------------------------------------------------------
__global__ __launch_bounds__(256) void gemm_qkv(
    const short* __restrict__ A, const short* __restrict__ Bt,
    const float* __restrict__ bq, const float* __restrict__ bk,
    const float* __restrict__ bv, short* __restrict__ qout,
    short* __restrict__ kout, short* __restrict__ vout, int M, int N, int K)
{
    __shared__ short As[128 * 32];
    __shared__ short Bs[128 * 32];
    const int tid = threadIdx.x;
    const int w = tid >> 6, l15 = tid & 15, quad = (tid & 63) >> 4;
    const int wm = w >> 1, wn = w & 1;
    const int m0 = blockIdx.y * 128, n0 = blockIdx.x * 128;

    floatx4 acc[4][4];
#pragma unroll
    for (int i = 0; i < 4; ++i)
#pragma unroll
        for (int j = 0; j < 4; ++j) acc[i][j] = (floatx4){0.f, 0.f, 0.f, 0.f};

    const int arow = tid >> 2, akc = tid & 3;
    const short* Ag0 = A + (size_t)(m0 + arow) * K + akc * 8;
    const short* Ag1 = A + (size_t)(m0 + 64 + arow) * K + akc * 8;
    const short* Bg0 = Bt + (size_t)(n0 + arow) * K + akc * 8;
    const short* Bg1 = Bt + (size_t)(n0 + 64 + arow) * K + akc * 8;
    short* AsW0 = As + (w * 64) * 8;
    short* AsW1 = As + (256 + w * 64) * 8;
    short* BsW0 = Bs + (w * 64) * 8;
    short* BsW1 = Bs + (256 + w * 64) * 8;

    for (int k0 = 0; k0 < K; k0 += 32) {
        GLL16(Ag0 + k0, AsW0);
        GLL16(Ag1 + k0, AsW1);
        GLL16(Bg0 + k0, BsW0);
        GLL16(Bg1 + k0, BsW1);
        __syncthreads();
        short8 af[4], bfr[4];
#pragma unroll
        for (int mt = 0; mt < 4; ++mt)
            af[mt] = *(const short8*)(As + (wm * 64 + mt * 16 + l15) * 32 + quad * 8);
#pragma unroll
        for (int nt = 0; nt < 4; ++nt)
            bfr[nt] = *(const short8*)(Bs + (wn * 64 + nt * 16 + l15) * 32 + quad * 8);
#pragma unroll
        for (int mt = 0; mt < 4; ++mt)
#pragma unroll
            for (int nt = 0; nt < 4; ++nt)
                acc[mt][nt] = __builtin_amdgcn_mfma_f32_16x16x32_bf16(
                    af[mt], bfr[nt], acc[mt][nt], 0, 0, 0);
        __syncthreads();
    }

#pragma unroll
    for (int nt = 0; nt < 4; ++nt) {
        int gcol = n0 + wn * 64 + nt * 16 + l15;
        float bvv = (gcol < 2048) ? bq[gcol]
                  : (gcol < 2560) ? bk[gcol - 2048] : bv[gcol - 2560];
#pragma unroll
        for (int mt = 0; mt < 4; ++mt) {
            int grow = m0 + wm * 64 + mt * 16 + quad * 4;
            floatx4 v = acc[mt][nt];
            if (n0 < 2048) {
#pragma unroll
                for (int r = 0; r < 4; ++r)
                    qout[(size_t)(grow + r) * 2048 + gcol] = f2bf(v[r] + bvv);
            } else if (n0 < 2560) {
                int c = gcol - 2048;
#pragma unroll
                for (int r = 0; r < 4; ++r)
                    kout[(size_t)(grow + r) * 512 + c] = f2bf(v[r] + bvv);
            } else {
                int c = gcol - 2560, gg = c >> 7, dv = c & 127;
                int bb = grow >> 11, s = grow & 2047;
                uint2 pk;
                pk.x = pkr(v[0] + bvv, v[1] + bvv);
                pk.y = pkr(v[2] + bvv, v[3] + bvv);
                *(uint2*)&vout[(((size_t)bb * G_ + gg) * HD_ + dv) * S_ + s] = pk;
            }
        }
    }
}

// ---------------------------------------------------------------------------
// bf16 MFMA GEMM (O-projection): C[M,N] fp32 = A[M,K] @ Bt[N,K]^T + bias
// ---------------------------------------------------------------------------
__global__ __launch_bounds__(256) void gemm_nt_f32(
    const short* __restrict__ A, const short* __restrict__ Bt,
    const float* __restrict__ bias, float* __restrict__ C,
    int M, int N, int K)
{
    __shared__ short As[128 * 32];
    __shared__ short Bs[128 * 32];
    const int tid = threadIdx.x;
    const int w = tid >> 6, l15 = tid & 15, quad = (tid & 63) >> 4;
    const int wm = w >> 1, wn = w & 1;
    const int m0 = blockIdx.y * 128, n0 = blockIdx.x * 128;

    floatx4 acc[4][4];
#pragma unroll
    for (int i = 0; i < 4; ++i)
#pragma unroll
        for (int j = 0; j < 4; ++j) acc[i][j] = (floatx4){0.f, 0.f, 0.f, 0.f};

    const int arow = tid >> 2, akc = tid & 3;
    const short* Ag0 = A + (size_t)(m0 + arow) * K + akc * 8;
    const short* Ag1 = A + (size_t)(m0 + 64 + arow) * K + akc * 8;
    const short* Bg0 = Bt + (size_t)(n0 + arow) * K + akc * 8;
    const short* Bg1 = Bt + (size_t)(n0 + 64 + arow) * K + akc * 8;
    short* AsW0 = As + (w * 64) * 8;
    short* AsW1 = As + (256 + w * 64) * 8;
    short* BsW0 = Bs + (w * 64) * 8;
    short* BsW1 = Bs + (256 + w * 64) * 8;

    for (int k0 = 0; k0 < K; k0 += 32) {
        GLL16(Ag0 + k0, AsW0);
        GLL16(Ag1 + k0, AsW1);
        GLL16(Bg0 + k0, BsW0);
        GLL16(Bg1 + k0, BsW1);
        __syncthreads();
        short8 af[4], bfr[4];
#pragma unroll
        for (int mt = 0; mt < 4; ++mt)
            af[mt] = *(const short8*)(As + (wm * 64 + mt * 16 + l15) * 32 + quad * 8);
#pragma unroll
        for (int nt = 0; nt < 4; ++nt)
            bfr[nt] = *(const short8*)(Bs + (wn * 64 + nt * 16 + l15) * 32 + quad * 8);
#pragma unroll
        for (int mt = 0; mt < 4; ++mt)
#pragma unroll
            for (int nt = 0; nt < 4; ++nt)
                acc[mt][nt] = __builtin_amdgcn_mfma_f32_16x16x32_bf16(
                    af[mt], bfr[nt], acc[mt][nt], 0, 0, 0);
        __syncthreads();
    }

#pragma unroll
    for (int nt = 0; nt < 4; ++nt) {
        int gcol = n0 + wn * 64 + nt * 16 + l15;
        float bvv = bias[gcol];
#pragma unroll
        for (int mt = 0; mt < 4; ++mt) {
            int grow = m0 + wm * 64 + mt * 16 + quad * 4;
            floatx4 v = acc[mt][nt];
#pragma unroll
            for (int r = 0; r < 4; ++r)
                C[(size_t)(grow + r) * N + gcol] = v[r] + bvv;
        }
    }
}

// ---------------------------------------------------------------------------
// RoPE in-place on bf16 (B,S,nh,HD); fp32 trig (err 1e-4 << bf16 ulp)
// Q additionally pre-scaled by 1/sqrt(HD) * log2(e): attention softmax runs
// in the exp2 domain (v_exp_f32 computes 2^x natively; saves a v_mul per exp).
// ---------------------------------------------------------------------------
__global__ void rope_bf16_kernel(short* __restrict__ p, int nh, float scale,
                                 int total)
{
    int gid = blockIdx.x * 256 + threadIdx.x;
    if (gid >= total) return;
    int i = gid & 63;
    int rest = gid >> 6;
    int head = rest % nh;
    int rest2 = rest / nh;
    int s = rest2 & (S_ - 1);
    int b = rest2 >> 11;
    size_t base = (((size_t)b * S_ + s) * nh + head) * HD_;
    float inv = __expf((float)i * -0.14391156509f);   // ln(1e4)/64
    float ang = (float)s * inv;
    float sn, cs;
    sincosf(ang, &sn, &cs);
    float t1 = b2f(p[base + i]), t2 = b2f(p[base + 64 + i]);
    p[base + i]      = f2bf((t1 * cs - t2 * sn) * scale);
    p[base + 64 + i] = f2bf((t2 * cs + t1 * sn) * scale);
}

// ---------------------------------------------------------------------------
// MFMA flash attention v6 = v2 structure (LDS-staged K/V via GLL16, proven
// 346us) + SCHEDULING FIX + exp2 softmax.
//
// R0-R3 post-mortem: v2's counters are self-consistent (MfmaUtil 8.4% ==
// 63Kcy/CU of issued MFMA over 830Kcy) and show avg occupancy 2.1 waves/CU
// vs a 12-wave LDS cap. Cause: grid (16,64) made qi a pure function of
// (block id mod 16); CU/XCD assignment is periodic in id (XCD = id%8,
// period 256 = 0 mod 16), so each CU repeatedly received the SAME qi --
// qi=15-lane CUs did 4x32 block-steps while qi=0-lane CUs did 4x2 and sat
// idle: ~8x per-CU load imbalance. That, not per-step latency, set the
// makespan (and explains why R1's pipelining was null).
//
// Fix: 1D grid id in [0,1024): bh = id & 63, qi = qtab[id>>6] with batch
// order {15,14,13,12 | 0,1,2,3 | 11,10,9,8 | 4,5,6,7}. Any period-256 CU
// assignment now gives each CU one block per batch-class, and every class
// sums to exactly 68 block-steps -> per-CU work uniform; heavy blocks still
// first. Pure bijection: correctness unchanged.
//
// Softmax in exp2 domain (Q pre-scaled by log2e at RoPE): exp2f = bare
// v_exp_f32. Defer-max threshold 11.5 bits (= 8 nats). Defer-max + vector
// sums kept from R1 (VALUBusy 20.8 -> 17.2 there).
// ---------------------------------------------------------------------------
#define PPITCH 72   // shorts; 144B = 16B-aligned, 4-bank stride -> 2-way

__global__ __launch_bounds__(256) void attn_mfma2(
    short* __restrict__ qb, const short* __restrict__ kb,
    const short* __restrict__ vt)
{
    __shared__ short Ks[64 * 128];      // [key][16B-chunk], chunk ^= key&7
    __shared__ short Vs[128 * 64];      // [dv][16B-chunk],  chunk ^= dv&7
    __shared__ short Ps[4][32 * PPITCH];// per-wave P as [q][key]

    const int tid = threadIdx.x;
    const int w = tid >> 6, lane = tid & 63, l15 = lane & 15, quad = lane >> 4;
    // ---- load-balanced qi remap (see header comment)
    const int id = (int)blockIdx.x;
    const int j = id >> 6, grp = j >> 2, pos = j & 3;
    const int qi = (grp == 0) ? (15 - pos)
                 : (grp == 1) ? pos
                 : (grp == 2) ? (11 - pos) : (4 + pos);
    const int q0 = qi * 128;
    const int bh = id & 63, b = bh >> 4, h = bh & 15, g = h >> 2;

    // Q fragments: rows q0 + w*32 + qs*16 + l15, d = quad*8 + 32c
    const short* qp = qb + ((((size_t)b * S_) + q0 + w * 32 + l15) * H_ + h) * HD_
                      + quad * 8;
    short8 qf[2][4];
#pragma unroll
    for (int qs = 0; qs < 2; ++qs)
#pragma unroll
        for (int c = 0; c < 4; ++c)
            qf[qs][c] = *(const short8*)(qp + qs * 16 * (H_ * HD_) + c * 32);

    floatx4 ot[2][8];
#pragma unroll
    for (int qs = 0; qs < 2; ++qs)
#pragma unroll
        for (int s = 0; s < 8; ++s) ot[qs][s] = (floatx4){0.f, 0.f, 0.f, 0.f};
    float m_i[2] = {-1e30f, -1e30f}, l_i[2] = {0.f, 0.f};

    // staging maps
    const int kkey = tid >> 4, kch = tid & 15;
    const int ksrc = kch ^ (kkey & 7);            // (key+16i)&7 == kkey&7
    const short* kgb = kb + (((size_t)b * S_) * G_ + g) * HD_ + ksrc * 8;
    const int vdv = tid >> 3, vch = tid & 7;
    const int vsrc = vch ^ (vdv & 7);             // (dv+32i)&7 == vdv&7
    const short* vgb = vt + (((size_t)(b * G_ + g)) * HD_ + vdv) * (size_t)S_
                       + vsrc * 8;
    const int sw = l15 & 7;
    short* pw = Ps[w];

    const int nkt = 2 * (qi + 1);
    for (int kt = 0; kt < nkt; ++kt) {
        __syncthreads();
        const short* kg = kgb + (size_t)(kt * 64) * (G_ * HD_);
        const short* vg = vgb + kt * 64;
#pragma unroll
        for (int i = 0; i < 4; ++i)
            GLL16(kg + (size_t)(kkey + 16 * i) * (G_ * HD_),
                  Ks + (w * 64 + 256 * i) * 8);
#pragma unroll
        for (int i = 0; i < 4; ++i)
            GLL16(vg + (size_t)(32 * i) * S_, Vs + (w * 64 + 256 * i) * 8);
        __syncthreads();

        // ---- S^T tiles: sa[qs][ksub], row = key = ksub*16+quad*4+r, col = q = l15
        floatx4 sa[2][4];
#pragma unroll
        for (int qs = 0; qs < 2; ++qs)
#pragma unroll
            for (int ks = 0; ks < 4; ++ks) sa[qs][ks] = (floatx4){0.f, 0.f, 0.f, 0.f};
#pragma unroll
        for (int c = 0; c < 4; ++c)
#pragma unroll
            for (int ks = 0; ks < 4; ++ks) {
                short8 kf = *(const short8*)(Ks +
                    ((l15 + 16 * ks) * 16 + ((c * 4 + quad) ^ sw)) * 8);
                sa[0][ks] = __builtin_amdgcn_mfma_f32_16x16x32_bf16(
                    kf, qf[0][c], sa[0][ks], 0, 0, 0);
                sa[1][ks] = __builtin_amdgcn_mfma_f32_16x16x32_bf16(
                    kf, qf[1][c], sa[1][ks], 0, 0, 0);
            }

        const int kbase = kt * 64;
#pragma unroll
        for (int qs = 0; qs < 2; ++qs) {
            const int qrow = q0 + w * 32 + qs * 16 + l15;
            // causal mask (only near diagonal; uniform per qs)
            if (kbase + 63 > q0 + w * 32 + qs * 16) {
#pragma unroll
                for (int ks = 0; ks < 4; ++ks)
#pragma unroll
                    for (int r = 0; r < 4; ++r)
                        if (kbase + ks * 16 + quad * 4 + r > qrow)
                            sa[qs][ks][r] = -1e30f;
            }
            // ---- lane-local online softmax (exp2 domain) over 16 keys + 2 shfl
            float mx = -1e30f;
#pragma unroll
            for (int ks = 0; ks < 4; ++ks)
#pragma unroll
                for (int r = 0; r < 4; ++r) mx = fmaxf(mx, sa[qs][ks][r]);
            mx = fmaxf(mx, __shfl_xor(mx, 16));
            mx = fmaxf(mx, __shfl_xor(mx, 32));
            float mo = m_i[qs];
            // defer-max: only rescale when some lane's max outgrew by >11.5 bits
            if (!__all(mx - mo <= 11.5f)) {
                float mn = fmaxf(mo, mx);
                float al = exp2f(mo - mn);
                m_i[qs] = mn;
                l_i[qs] *= al;
#pragma unroll
                for (int s = 0; s < 8; ++s) {
                    floatx4 o = ot[qs][s];
                    o[0] *= al; o[1] *= al; o[2] *= al; o[3] *= al;
                    ot[qs][s] = o;
                }
                mo = mn;
            }
            float s0 = 0.f, s1 = 0.f, s2 = 0.f, s3 = 0.f;
#pragma unroll
            for (int ks = 0; ks < 4; ++ks) {
                float p0 = exp2f(sa[qs][ks][0] - mo);
                float p1 = exp2f(sa[qs][ks][1] - mo);
                float p2 = exp2f(sa[qs][ks][2] - mo);
                float p3 = exp2f(sa[qs][ks][3] - mo);
                sa[qs][ks][0] = p0; sa[qs][ks][1] = p1;
                sa[qs][ks][2] = p2; sa[qs][ks][3] = p3;
                s0 += p0; s1 += p1; s2 += p2; s3 += p3;
            }
            float sum = (s0 + s1) + (s2 + s3);
            sum += __shfl_xor(sum, 16);
            sum += __shfl_xor(sum, 32);
            l_i[qs] += sum;
            // ---- P -> per-wave LDS as [q][key] (b64 writes)
            short* pr = pw + (qs * 16 + l15) * PPITCH;
#pragma unroll
            for (int ks = 0; ks < 4; ++ks) {
                uint2 pkv;
                pkv.x = pk2(sa[qs][ks][0], sa[qs][ks][1]);
                pkv.y = pk2(sa[qs][ks][2], sa[qs][ks][3]);
                *(uint2*)(pr + ks * 16 + quad * 4) = pkv;
            }
        }

        // ---- O^T += V^T · P^T  (V-frags shared across both q-subtiles)
#pragma unroll
        for (int kc = 0; kc < 2; ++kc) {
            short8 pf0 = *(const short8*)(pw + l15 * PPITCH + kc * 32 + quad * 8);
            short8 pf1 = *(const short8*)(pw + (16 + l15) * PPITCH + kc * 32 + quad * 8);
#pragma unroll
            for (int s = 0; s < 8; ++s) {
                short8 vf = *(const short8*)(Vs +
                    ((l15 + 16 * s) * 8 + ((kc * 4 + quad) ^ sw)) * 8);
                ot[0][s] = __builtin_amdgcn_mfma_f32_16x16x32_bf16(
                    vf, pf0, ot[0][s], 0, 0, 0);
                ot[1][s] = __builtin_amdgcn_mfma_f32_16x16x32_bf16(
                    vf, pf1, ot[1][s], 0, 0, 0);
            }
        }
    }

    // ---- epilogue: normalize (lane-local l), write bf16 in-place
#pragma unroll
    for (int qs = 0; qs < 2; ++qs) {
        float inv = 1.f / l_i[qs];
        size_t base = ((((size_t)b * S_) + q0 + w * 32 + qs * 16 + l15) * H_ + h)
                      * HD_;
#pragma unroll
        for (int s = 0; s < 8; ++s) {
            uint2 pkv;
            pkv.x = pkr(ot[qs][s][0] * inv, ot[qs][s][1] * inv);
            pkv.y = pkr(ot[qs][s][2] * inv, ot[qs][s][3] * inv);
            *(uint2*)&qb[base + s * 16 + quad * 4] = pkv;
        }
    }
}

// ---------------------------------------------------------------------------
extern "C" void kernel_launch(void* const* d_in, const int* in_sizes, int n_in,
                              void* d_out, int out_size, void* d_ws, size_t ws_size,
                              hipStream_t stream)
{
    const float* x  = (const float*)d_in[0];
    const float* Wq = (const float*)d_in[1];
    const float* bq = (const float*)d_in[2];
    const float* Wk = (const float*)d_in[3];
    const float* bk = (const float*)d_in[4];
    const float* Wv = (const float*)d_in[5];
    const float* bv = (const float*)d_in[6];
    const float* Wo = (const float*)d_in[7];
    const float* bo = (const float*)d_in[8];
    float* out = (float*)d_out;

    // ws layout (bf16 elements); total 96.5 MB
    short* xb  = (short*)d_ws;        // 16,777,216
    short* Wt  = xb + 16777216;       // 3072*2048 = 6,291,456 (reused for Wo^T)
    short* qb8 = Wt + 6291456;        // 16,777,216 (q -> attn out, in-place)
    short* kb8 = qb8 + 16777216;      // 4,194,304
    short* vt8 = kb8 + 4194304;       // 4,194,304  V^T (b,g,dv,s)

    const int M = B_ * S_;
    dim3 blk(256);

    cvt_bf16_kernel<<<8192, blk, 0, stream>>>(x, xb, 16777216 / 8);
    tr_bf16_kernel<<<dim3(64, 64), blk, 0, stream>>>(Wq, Wt, 2048, 2048);
    tr_bf16_kernel<<<dim3(16, 64), blk, 0, stream>>>(Wk, Wt + (size_t)2048 * 2048, 2048, 512);
    tr_bf16_kernel<<<dim3(16, 64), blk, 0, stream>>>(Wv, Wt + (size_t)2560 * 2048, 2048, 512);

    gemm_qkv<<<dim3(24, 64), blk, 0, stream>>>(xb, Wt, bq, bk, bv,
                                               qb8, kb8, vt8, M, 3072, 2048);

    // Wt slot free now -> Wo^T (stream-ordered)
    tr_bf16_kernel<<<dim3(64, 64), blk, 0, stream>>>(Wo, Wt, 2048, 2048);

    // Q scale folds 1/sqrt(128) * log2(e): softmax runs in exp2 domain
    const float qscale = 0.12751744417f;
    rope_bf16_kernel<<<32768, blk, 0, stream>>>(qb8, H_, qscale, M * H_ * 64);
    rope_bf16_kernel<<<8192,  blk, 0, stream>>>(kb8, G_, 1.0f,   M * G_ * 64);

    attn_mfma2<<<dim3(1024), blk, 0, stream>>>(qb8, kb8, vt8);

    gemm_nt_f32<<<dim3(16, 64), blk, 0, stream>>>(qb8, Wt, bo, out, M, 2048, 2048);
}

// Round 5
// 591.929 us; speedup vs baseline: 2.2797x; 1.0755x over previous
//
#include <hip/hip_runtime.h>
#include <hip/hip_bf16.h>
#include <math.h>

#define B_  4
#define S_  2048
#define D_  2048
#define H_  16
#define G_  4
#define HD_ 128

typedef __attribute__((ext_vector_type(8))) short short8;
typedef __attribute__((ext_vector_type(4))) float floatx4;

__device__ __forceinline__ short f2bf(float f) {
    unsigned u = __float_as_uint(f);
    unsigned r = (u + 0x7fff + ((u >> 16) & 1)) >> 16;
    return (short)r;
}
__device__ __forceinline__ float b2f(short s) {
    return __uint_as_float(((unsigned)(unsigned short)s) << 16);
}
// pack two floats to bf16x2, round-half-up (cheap; used for P)
__device__ __forceinline__ unsigned pk2(float a, float b) {
    unsigned ua = (__float_as_uint(a) + 0x8000u) >> 16;
    unsigned ub = (__float_as_uint(b) + 0x8000u) & 0xffff0000u;
    return ua | ub;
}
// pack two floats to bf16x2, RNE (outputs)
__device__ __forceinline__ unsigned pkr(float a, float b) {
    return (unsigned)(unsigned short)f2bf(a) |
           ((unsigned)(unsigned short)f2bf(b) << 16);
}

#define GLL16(gp, lp) __builtin_amdgcn_global_load_lds( \
    (const __attribute__((address_space(1))) void*)(gp), \
    (__attribute__((address_space(3))) void*)(lp), 16, 0, 0)

// ---------------------------------------------------------------------------
// fp32 -> bf16 convert (8 elems/thread)
// ---------------------------------------------------------------------------
__global__ void cvt_bf16_kernel(const float* __restrict__ in,
                                short* __restrict__ out, int n8)
{
    int t = blockIdx.x * 256 + threadIdx.x;
    if (t >= n8) return;
    const float4* p = (const float4*)in + (size_t)t * 2;
    float4 a = p[0], b = p[1];
    short8 r;
    r[0] = f2bf(a.x); r[1] = f2bf(a.y); r[2] = f2bf(a.z); r[3] = f2bf(a.w);
    r[4] = f2bf(b.x); r[5] = f2bf(b.y); r[6] = f2bf(b.z); r[7] = f2bf(b.w);
    ((short8*)out)[t] = r;
}

// ---------------------------------------------------------------------------
// W[K][N] fp32 -> Wt[N][K] bf16, 32x32 LDS tiles
// ---------------------------------------------------------------------------
__global__ __launch_bounds__(256) void tr_bf16_kernel(
    const float* __restrict__ in, short* __restrict__ out, int K, int N)
{
    __shared__ float T[32][33];
    int n0 = blockIdx.x * 32, k0 = blockIdx.y * 32;
    int tx = threadIdx.x & 31, ty = threadIdx.x >> 5;
#pragma unroll
    for (int i = 0; i < 4; ++i)
        T[ty + i * 8][tx] = in[(size_t)(k0 + ty + i * 8) * N + n0 + tx];
    __syncthreads();
#pragma unroll
    for (int i = 0; i < 4; ++i)
        out[(size_t)(n0 + ty + i * 8) * K + k0 + tx] = f2bf(T[tx][ty + i * 8]);
}

// ---------------------------------------------------------------------------
// 256x256 deep-pipelined bf16 GEMM (8-phase / counted-vmcnt schedule).
// C[M,N] = A[M,K] @ Bt[N,K]^T (+bias), two epilogues (fp32-out / qkv-split).
//
// Why: the previous 128^2 m97-structure GEMMs drain vmcnt(0) at every
// __syncthreads (compiler-forced) -> measured-class ~500 TF here. This
// schedule keeps global_load_lds traffic in flight ACROSS barriers:
//   512 thr / 8 waves (2Mx4N), per-wave C = 128x64 (acc[8][4]).
//   LDS 128KB: 2 buffers x {A,B} x [k-half][256 rows][32 k] bf16.
//   XOR swizzle: LDS chunk c holds global chunk c^(row&3); reads use
//   csw = quad^(l15&3)  -> conflict-free ds_read_b128 both sides.
//   Per tile (BK=64): 4 phases {8x ds_read_b128, stage 1 half-tile of t+1
//   (2x GLL16), setprio(1), 16 MFMA, setprio(0), s_waitcnt vmcnt(4),
//   s_barrier}.  vmcnt(4) retires exactly the oldest half-tile each phase;
//   every half has >=2 phases of flight before first read; NEVER 0 in-loop.
//   Stage order Ak0,Bk0,Ak1,Bk1; reads ks0 in p0/p1, ks1 in p2/p3.
//   Last tile peeled: one vmcnt(0) + barrier, then compute-only.
// K-accumulation order identical to the old kernel (bitwise-same results).
// ---------------------------------------------------------------------------
__global__ __launch_bounds__(512, 2) void gemm256_8ph(
    const short* __restrict__ A, const short* __restrict__ Bt,
    int M, int N, int K, int qkvmode,
    const float* __restrict__ b0, const float* __restrict__ b1,
    const float* __restrict__ b2, float* __restrict__ Cf,
    short* __restrict__ qo, short* __restrict__ ko, short* __restrict__ vo)
{
    __shared__ short L[65536];          // 128 KB
    const int tid = threadIdx.x;
    const int w = tid >> 6, lane = tid & 63, l15 = lane & 15, quad = lane >> 4;
    const int wm = w >> 2, wn = w & 3;
    const int n0 = blockIdx.x * 256, m0 = blockIdx.y * 256;
    const int NT = K >> 6;

    // staging map: thread covers rows (tid>>2) and (tid>>2)+128 of a half,
    // LDS chunk (tid&3); global chunk = (tid&3) ^ (row&3)  (involution)
    const int srow = tid >> 2;
    const int gch8 = ((tid & 3) ^ (srow & 3)) * 8;
    // read-side swizzled chunk (row&3 == l15&3 for all frag rows)
    const int csw8 = (quad ^ (l15 & 3)) * 8;

    floatx4 acc[8][4];
#pragma unroll
    for (int f = 0; f < 8; ++f)
#pragma unroll
        for (int g = 0; g < 4; ++g) acc[f][g] = (floatx4){0.f, 0.f, 0.f, 0.f};

    const short* Ab = A  + (size_t)(m0 + srow) * K + gch8;
    const short* Bb = Bt + (size_t)(n0 + srow) * K + gch8;
    const size_t rj = (size_t)128 * K;

#define STGA(tt, KH, DB) do { \
    const short* s_ = Ab + (size_t)(tt) * 64 + (KH) * 32; \
    short* d_ = L + (DB) * 32768 + (KH) * 8192 + tid * 8; \
    GLL16(s_, d_); GLL16(s_ + rj, d_ + 4096); } while (0)
#define STGB(tt, KH, DB) do { \
    const short* s_ = Bb + (size_t)(tt) * 64 + (KH) * 32; \
    short* d_ = L + (DB) * 32768 + 16384 + (KH) * 8192 + tid * 8; \
    GLL16(s_, d_); GLL16(s_ + rj, d_ + 4096); } while (0)

    // prologue: tile 0 -> buf0, order Ak0,Bk0,Ak1,Bk1 (8 loads)
    STGA(0, 0, 0); STGB(0, 0, 0); STGA(0, 1, 0); STGB(0, 1, 0);
    asm volatile("s_waitcnt vmcnt(4)" ::: "memory");   // Ak0,Bk0 landed
    asm volatile("s_barrier" ::: "memory");

#define PH(KS, FH, STAGE_STMT) do { \
    short8 afr[4], bfr[4]; \
    _Pragma("unroll") \
    for (int i = 0; i < 4; ++i) \
        afr[i] = *(const short8*)(ab + (KS) * 8192 + \
                 (wm * 128 + ((FH) * 4 + i) * 16 + l15) * 32 + csw8); \
    _Pragma("unroll") \
    for (int g = 0; g < 4; ++g) \
        bfr[g] = *(const short8*)(bb + (KS) * 8192 + \
                 (wn * 64 + g * 16 + l15) * 32 + csw8); \
    STAGE_STMT; \
    __builtin_amdgcn_s_setprio(1); \
    _Pragma("unroll") \
    for (int i = 0; i < 4; ++i) { \
        acc[(FH)*4+i][0] = __builtin_amdgcn_mfma_f32_16x16x32_bf16(afr[i], bfr[0], acc[(FH)*4+i][0], 0, 0, 0); \
        acc[(FH)*4+i][1] = __builtin_amdgcn_mfma_f32_16x16x32_bf16(afr[i], bfr[1], acc[(FH)*4+i][1], 0, 0, 0); \
        acc[(FH)*4+i][2] = __builtin_amdgcn_mfma_f32_16x16x32_bf16(afr[i], bfr[2], acc[(FH)*4+i][2], 0, 0, 0); \
        acc[(FH)*4+i][3] = __builtin_amdgcn_mfma_f32_16x16x32_bf16(afr[i], bfr[3], acc[(FH)*4+i][3], 0, 0, 0); \
    } \
    __builtin_amdgcn_s_setprio(0); } while (0)

#define PHW \
    asm volatile("s_waitcnt vmcnt(4)" ::: "memory"); \
    asm volatile("s_barrier" ::: "memory");

    for (int t = 0; t < NT - 1; ++t) {
        const int cur = t & 1, nxt = cur ^ 1;
        const short* ab = L + cur * 32768;
        const short* bb = ab + 16384;
        PH(0, 0, STGA(t + 1, 0, nxt)); PHW;
        PH(0, 1, STGB(t + 1, 0, nxt)); PHW;
        PH(1, 0, STGA(t + 1, 1, nxt)); PHW;
        PH(1, 1, STGB(t + 1, 1, nxt)); PHW;
    }
    // last tile: drain once, then compute-only
    asm volatile("s_waitcnt vmcnt(0)" ::: "memory");
    asm volatile("s_barrier" ::: "memory");
    {
        const int cur = (NT - 1) & 1;
        const short* ab = L + cur * 32768;
        const short* bb = ab + 16384;
        PH(0, 0, (void)0); PH(0, 1, (void)0);
        PH(1, 0, (void)0); PH(1, 1, (void)0);
    }

    // ---- epilogue
    if (!qkvmode) {
#pragma unroll
        for (int f = 0; f < 8; ++f) {
            int grow = m0 + wm * 128 + f * 16 + quad * 4;
#pragma unroll
            for (int g = 0; g < 4; ++g) {
                int gcol = n0 + wn * 64 + g * 16 + l15;
                float bvv = b0[gcol];
                floatx4 v = acc[f][g];
#pragma unroll
                for (int r = 0; r < 4; ++r)
                    Cf[(size_t)(grow + r) * N + gcol] = v[r] + bvv;
            }
        }
    } else {
#pragma unroll
        for (int g = 0; g < 4; ++g) {
            int gcol = n0 + wn * 64 + g * 16 + l15;
            float bvv = (gcol < 2048) ? b0[gcol]
                      : (gcol < 2560) ? b1[gcol - 2048] : b2[gcol - 2560];
#pragma unroll
            for (int f = 0; f < 8; ++f) {
                int grow = m0 + wm * 128 + f * 16 + quad * 4;
                floatx4 v = acc[f][g];
                if (n0 < 2048) {
#pragma unroll
                    for (int r = 0; r < 4; ++r)
                        qo[(size_t)(grow + r) * 2048 + gcol] = f2bf(v[r] + bvv);
                } else if (n0 < 2560) {
                    int c = gcol - 2048;
#pragma unroll
                    for (int r = 0; r < 4; ++r)
                        ko[(size_t)(grow + r) * 512 + c] = f2bf(v[r] + bvv);
                } else {
                    int c = gcol - 2560, gg = c >> 7, dv = c & 127;
                    int bb2 = grow >> 11, s = grow & 2047;
                    uint2 pk;
                    pk.x = pkr(v[0] + bvv, v[1] + bvv);
                    pk.y = pkr(v[2] + bvv, v[3] + bvv);
                    *(uint2*)&vo[(((size_t)bb2 * G_ + gg) * HD_ + dv) * S_ + s] = pk;
                }
            }
        }
    }
#undef PH
#undef PHW
#undef STGA
#undef STGB
}

// ---------------------------------------------------------------------------
// RoPE in-place on bf16 (B,S,nh,HD); fp32 trig (err 1e-4 << bf16 ulp)
// Q additionally pre-scaled by 1/sqrt(HD) * log2(e): attention softmax runs
// in the exp2 domain (v_exp_f32 computes 2^x natively; saves a v_mul per exp).
// ---------------------------------------------------------------------------
__global__ void rope_bf16_kernel(short* __restrict__ p, int nh, float scale,
                                 int total)
{
    int gid = blockIdx.x * 256 + threadIdx.x;
    if (gid >= total) return;
    int i = gid & 63;
    int rest = gid >> 6;
    int head = rest % nh;
    int rest2 = rest / nh;
    int s = rest2 & (S_ - 1);
    int b = rest2 >> 11;
    size_t base = (((size_t)b * S_ + s) * nh + head) * HD_;
    float inv = __expf((float)i * -0.14391156509f);   // ln(1e4)/64
    float ang = (float)s * inv;
    float sn, cs;
    sincosf(ang, &sn, &cs);
    float t1 = b2f(p[base + i]), t2 = b2f(p[base + 64 + i]);
    p[base + i]      = f2bf((t1 * cs - t2 * sn) * scale);
    p[base + 64 + i] = f2bf((t2 * cs + t1 * sn) * scale);
}

// ---------------------------------------------------------------------------
// MFMA flash attention v6 (R4, 214us): LDS-staged K/V via GLL16 + balanced
// 1D-grid qi remap + exp2-domain softmax + defer-max.  Unchanged this round.
// ---------------------------------------------------------------------------
#define PPITCH 72   // shorts; 144B = 16B-aligned, 4-bank stride -> 2-way

__global__ __launch_bounds__(256) void attn_mfma2(
    short* __restrict__ qb, const short* __restrict__ kb,
    const short* __restrict__ vt)
{
    __shared__ short Ks[64 * 128];      // [key][16B-chunk], chunk ^= key&7
    __shared__ short Vs[128 * 64];      // [dv][16B-chunk],  chunk ^= dv&7
    __shared__ short Ps[4][32 * PPITCH];// per-wave P as [q][key]

    const int tid = threadIdx.x;
    const int w = tid >> 6, lane = tid & 63, l15 = lane & 15, quad = lane >> 4;
    // ---- load-balanced qi remap
    const int id = (int)blockIdx.x;
    const int j = id >> 6, grp = j >> 2, pos = j & 3;
    const int qi = (grp == 0) ? (15 - pos)
                 : (grp == 1) ? pos
                 : (grp == 2) ? (11 - pos) : (4 + pos);
    const int q0 = qi * 128;
    const int bh = id & 63, b = bh >> 4, h = bh & 15, g = h >> 2;

    // Q fragments: rows q0 + w*32 + qs*16 + l15, d = quad*8 + 32c
    const short* qp = qb + ((((size_t)b * S_) + q0 + w * 32 + l15) * H_ + h) * HD_
                      + quad * 8;
    short8 qf[2][4];
#pragma unroll
    for (int qs = 0; qs < 2; ++qs)
#pragma unroll
        for (int c = 0; c < 4; ++c)
            qf[qs][c] = *(const short8*)(qp + qs * 16 * (H_ * HD_) + c * 32);

    floatx4 ot[2][8];
#pragma unroll
    for (int qs = 0; qs < 2; ++qs)
#pragma unroll
        for (int s = 0; s < 8; ++s) ot[qs][s] = (floatx4){0.f, 0.f, 0.f, 0.f};
    float m_i[2] = {-1e30f, -1e30f}, l_i[2] = {0.f, 0.f};

    // staging maps
    const int kkey = tid >> 4, kch = tid & 15;
    const int ksrc = kch ^ (kkey & 7);            // (key+16i)&7 == kkey&7
    const short* kgb = kb + (((size_t)b * S_) * G_ + g) * HD_ + ksrc * 8;
    const int vdv = tid >> 3, vch = tid & 7;
    const int vsrc = vch ^ (vdv & 7);             // (dv+32i)&7 == vdv&7
    const short* vgb = vt + (((size_t)(b * G_ + g)) * HD_ + vdv) * (size_t)S_
                       + vsrc * 8;
    const int sw = l15 & 7;
    short* pw = Ps[w];

    const int nkt = 2 * (qi + 1);
    for (int kt = 0; kt < nkt; ++kt) {
        __syncthreads();
        const short* kg = kgb + (size_t)(kt * 64) * (G_ * HD_);
        const short* vg = vgb + kt * 64;
#pragma unroll
        for (int i = 0; i < 4; ++i)
            GLL16(kg + (size_t)(kkey + 16 * i) * (G_ * HD_),
                  Ks + (w * 64 + 256 * i) * 8);
#pragma unroll
        for (int i = 0; i < 4; ++i)
            GLL16(vg + (size_t)(32 * i) * S_, Vs + (w * 64 + 256 * i) * 8);
        __syncthreads();

        // ---- S^T tiles: sa[qs][ksub], row = key = ksub*16+quad*4+r, col = q = l15
        floatx4 sa[2][4];
#pragma unroll
        for (int qs = 0; qs < 2; ++qs)
#pragma unroll
            for (int ks = 0; ks < 4; ++ks) sa[qs][ks] = (floatx4){0.f, 0.f, 0.f, 0.f};
#pragma unroll
        for (int c = 0; c < 4; ++c)
#pragma unroll
            for (int ks = 0; ks < 4; ++ks) {
                short8 kf = *(const short8*)(Ks +
                    ((l15 + 16 * ks) * 16 + ((c * 4 + quad) ^ sw)) * 8);
                sa[0][ks] = __builtin_amdgcn_mfma_f32_16x16x32_bf16(
                    kf, qf[0][c], sa[0][ks], 0, 0, 0);
                sa[1][ks] = __builtin_amdgcn_mfma_f32_16x16x32_bf16(
                    kf, qf[1][c], sa[1][ks], 0, 0, 0);
            }

        const int kbase = kt * 64;
#pragma unroll
        for (int qs = 0; qs < 2; ++qs) {
            const int qrow = q0 + w * 32 + qs * 16 + l15;
            // causal mask (only near diagonal; uniform per qs)
            if (kbase + 63 > q0 + w * 32 + qs * 16) {
#pragma unroll
                for (int ks = 0; ks < 4; ++ks)
#pragma unroll
                    for (int r = 0; r < 4; ++r)
                        if (kbase + ks * 16 + quad * 4 + r > qrow)
                            sa[qs][ks][r] = -1e30f;
            }
            // ---- lane-local online softmax (exp2 domain) over 16 keys + 2 shfl
            float mx = -1e30f;
#pragma unroll
            for (int ks = 0; ks < 4; ++ks)
#pragma unroll
                for (int r = 0; r < 4; ++r) mx = fmaxf(mx, sa[qs][ks][r]);
            mx = fmaxf(mx, __shfl_xor(mx, 16));
            mx = fmaxf(mx, __shfl_xor(mx, 32));
            float mo = m_i[qs];
            // defer-max: only rescale when some lane's max outgrew by >11.5 bits
            if (!__all(mx - mo <= 11.5f)) {
                float mn = fmaxf(mo, mx);
                float al = exp2f(mo - mn);
                m_i[qs] = mn;
                l_i[qs] *= al;
#pragma unroll
                for (int s = 0; s < 8; ++s) {
                    floatx4 o = ot[qs][s];
                    o[0] *= al; o[1] *= al; o[2] *= al; o[3] *= al;
                    ot[qs][s] = o;
                }
                mo = mn;
            }
            float s0 = 0.f, s1 = 0.f, s2 = 0.f, s3 = 0.f;
#pragma unroll
            for (int ks = 0; ks < 4; ++ks) {
                float p0 = exp2f(sa[qs][ks][0] - mo);
                float p1 = exp2f(sa[qs][ks][1] - mo);
                float p2 = exp2f(sa[qs][ks][2] - mo);
                float p3 = exp2f(sa[qs][ks][3] - mo);
                sa[qs][ks][0] = p0; sa[qs][ks][1] = p1;
                sa[qs][ks][2] = p2; sa[qs][ks][3] = p3;
                s0 += p0; s1 += p1; s2 += p2; s3 += p3;
            }
            float sum = (s0 + s1) + (s2 + s3);
            sum += __shfl_xor(sum, 16);
            sum += __shfl_xor(sum, 32);
            l_i[qs] += sum;
            // ---- P -> per-wave LDS as [q][key] (b64 writes)
            short* pr = pw + (qs * 16 + l15) * PPITCH;
#pragma unroll
            for (int ks = 0; ks < 4; ++ks) {
                uint2 pkv;
                pkv.x = pk2(sa[qs][ks][0], sa[qs][ks][1]);
                pkv.y = pk2(sa[qs][ks][2], sa[qs][ks][3]);
                *(uint2*)(pr + ks * 16 + quad * 4) = pkv;
            }
        }

        // ---- O^T += V^T · P^T  (V-frags shared across both q-subtiles)
#pragma unroll
        for (int kc = 0; kc < 2; ++kc) {
            short8 pf0 = *(const short8*)(pw + l15 * PPITCH + kc * 32 + quad * 8);
            short8 pf1 = *(const short8*)(pw + (16 + l15) * PPITCH + kc * 32 + quad * 8);
#pragma unroll
            for (int s = 0; s < 8; ++s) {
                short8 vf = *(const short8*)(Vs +
                    ((l15 + 16 * s) * 8 + ((kc * 4 + quad) ^ sw)) * 8);
                ot[0][s] = __builtin_amdgcn_mfma_f32_16x16x32_bf16(
                    vf, pf0, ot[0][s], 0, 0, 0);
                ot[1][s] = __builtin_amdgcn_mfma_f32_16x16x32_bf16(
                    vf, pf1, ot[1][s], 0, 0, 0);
            }
        }
    }

    // ---- epilogue: normalize (lane-local l), write bf16 in-place
#pragma unroll
    for (int qs = 0; qs < 2; ++qs) {
        float inv = 1.f / l_i[qs];
        size_t base = ((((size_t)b * S_) + q0 + w * 32 + qs * 16 + l15) * H_ + h)
                      * HD_;
#pragma unroll
        for (int s = 0; s < 8; ++s) {
            uint2 pkv;
            pkv.x = pkr(ot[qs][s][0] * inv, ot[qs][s][1] * inv);
            pkv.y = pkr(ot[qs][s][2] * inv, ot[qs][s][3] * inv);
            *(uint2*)&qb[base + s * 16 + quad * 4] = pkv;
        }
    }
}

// ---------------------------------------------------------------------------
extern "C" void kernel_launch(void* const* d_in, const int* in_sizes, int n_in,
                              void* d_out, int out_size, void* d_ws, size_t ws_size,
                              hipStream_t stream)
{
    const float* x  = (const float*)d_in[0];
    const float* Wq = (const float*)d_in[1];
    const float* bq = (const float*)d_in[2];
    const float* Wk = (const float*)d_in[3];
    const float* bk = (const float*)d_in[4];
    const float* Wv = (const float*)d_in[5];
    const float* bv = (const float*)d_in[6];
    const float* Wo = (const float*)d_in[7];
    const float* bo = (const float*)d_in[8];
    float* out = (float*)d_out;

    // ws layout (bf16 elements); total 96.5 MB
    short* xb  = (short*)d_ws;        // 16,777,216
    short* Wt  = xb + 16777216;       // 3072*2048 = 6,291,456 (reused for Wo^T)
    short* qb8 = Wt + 6291456;        // 16,777,216 (q -> attn out, in-place)
    short* kb8 = qb8 + 16777216;      // 4,194,304
    short* vt8 = kb8 + 4194304;       // 4,194,304  V^T (b,g,dv,s)

    const int M = B_ * S_;
    dim3 blk(256);

    cvt_bf16_kernel<<<8192, blk, 0, stream>>>(x, xb, 16777216 / 8);
    tr_bf16_kernel<<<dim3(64, 64), blk, 0, stream>>>(Wq, Wt, 2048, 2048);
    tr_bf16_kernel<<<dim3(16, 64), blk, 0, stream>>>(Wk, Wt + (size_t)2048 * 2048, 2048, 512);
    tr_bf16_kernel<<<dim3(16, 64), blk, 0, stream>>>(Wv, Wt + (size_t)2560 * 2048, 2048, 512);

    // merged QKV GEMM: 256^2 8-phase, grid (N/256, M/256)
    gemm256_8ph<<<dim3(12, 32), dim3(512), 0, stream>>>(
        xb, Wt, M, 3072, 2048, 1, bq, bk, bv, nullptr, qb8, kb8, vt8);

    // Wt slot free now -> Wo^T (stream-ordered)
    tr_bf16_kernel<<<dim3(64, 64), blk, 0, stream>>>(Wo, Wt, 2048, 2048);

    // Q scale folds 1/sqrt(128) * log2(e): softmax runs in exp2 domain
    const float qscale = 0.12751744417f;
    rope_bf16_kernel<<<32768, blk, 0, stream>>>(qb8, H_, qscale, M * H_ * 64);
    rope_bf16_kernel<<<8192,  blk, 0, stream>>>(kb8, G_, 1.0f,   M * G_ * 64);

    attn_mfma2<<<dim3(1024), blk, 0, stream>>>(qb8, kb8, vt8);

    // O-projection: 256^2 8-phase, grid (8, 32); id%8 = bx -> per-XCD B-panel
    gemm256_8ph<<<dim3(8, 32), dim3(512), 0, stream>>>(
        qb8, Wt, M, 2048, 2048, 0, bo, nullptr, nullptr, out,
        nullptr, nullptr, nullptr);
}

// Round 8
// 588.365 us; speedup vs baseline: 2.2935x; 1.0061x over previous
//
#include <hip/hip_runtime.h>
#include <hip/hip_bf16.h>
#include <math.h>

#define B_  4
#define S_  2048
#define D_  2048
#define H_  16
#define G_  4
#define HD_ 128

typedef __attribute__((ext_vector_type(8))) short short8;
typedef __attribute__((ext_vector_type(4))) float floatx4;

__device__ __forceinline__ short f2bf(float f) {
    unsigned u = __float_as_uint(f);
    unsigned r = (u + 0x7fff + ((u >> 16) & 1)) >> 16;
    return (short)r;
}
__device__ __forceinline__ float b2f(short s) {
    return __uint_as_float(((unsigned)(unsigned short)s) << 16);
}
// pack two floats to bf16x2, round-half-up (cheap; used for P)
__device__ __forceinline__ unsigned pk2(float a, float b) {
    unsigned ua = (__float_as_uint(a) + 0x8000u) >> 16;
    unsigned ub = (__float_as_uint(b) + 0x8000u) & 0xffff0000u;
    return ua | ub;
}
// pack two floats to bf16x2, RNE (outputs)
__device__ __forceinline__ unsigned pkr(float a, float b) {
    return (unsigned)(unsigned short)f2bf(a) |
           ((unsigned)(unsigned short)f2bf(b) << 16);
}

#define GLL16(gp, lp) __builtin_amdgcn_global_load_lds( \
    (const __attribute__((address_space(1))) void*)(gp), \
    (__attribute__((address_space(3))) void*)(lp), 16, 0, 0)

// ---------------------------------------------------------------------------
// fp32 -> bf16 convert (8 elems/thread)
// ---------------------------------------------------------------------------
__global__ void cvt_bf16_kernel(const float* __restrict__ in,
                                short* __restrict__ out, int n8)
{
    int t = blockIdx.x * 256 + threadIdx.x;
    if (t >= n8) return;
    const float4* p = (const float4*)in + (size_t)t * 2;
    float4 a = p[0], b = p[1];
    short8 r;
    r[0] = f2bf(a.x); r[1] = f2bf(a.y); r[2] = f2bf(a.z); r[3] = f2bf(a.w);
    r[4] = f2bf(b.x); r[5] = f2bf(b.y); r[6] = f2bf(b.z); r[7] = f2bf(b.w);
    ((short8*)out)[t] = r;
}

// ---------------------------------------------------------------------------
// W[K][N] fp32 -> Wt[N][K] bf16, 32x32 LDS tiles
// ---------------------------------------------------------------------------
__global__ __launch_bounds__(256) void tr_bf16_kernel(
    const float* __restrict__ in, short* __restrict__ out, int K, int N)
{
    __shared__ float T[32][33];
    int n0 = blockIdx.x * 32, k0 = blockIdx.y * 32;
    int tx = threadIdx.x & 31, ty = threadIdx.x >> 5;
#pragma unroll
    for (int i = 0; i < 4; ++i)
        T[ty + i * 8][tx] = in[(size_t)(k0 + ty + i * 8) * N + n0 + tx];
    __syncthreads();
#pragma unroll
    for (int i = 0; i < 4; ++i)
        out[(size_t)(n0 + ty + i * 8) * K + k0 + tx] = f2bf(T[tx][ty + i * 8]);
}

// ---------------------------------------------------------------------------
// 256x256 deep-pipelined bf16 GEMM — R5 cadence (vmcnt(4)+barrier EVERY
// phase; this exact schedule passed on HW at 592us total). The R6 "BARN"
// fewer-waits variant is parked: it coincided with two container failures
// and is the only unproven sync structure in that build.
// C[M,N] = A[M,K] @ Bt[N,K]^T (+bias), two epilogues (fp32-out / qkv-split).
// ---------------------------------------------------------------------------
__global__ __launch_bounds__(512, 2) void gemm256_8ph(
    const short* __restrict__ A, const short* __restrict__ Bt,
    int M, int N, int K, int qkvmode,
    const float* __restrict__ b0, const float* __restrict__ b1,
    const float* __restrict__ b2, float* __restrict__ Cf,
    short* __restrict__ qo, short* __restrict__ ko, short* __restrict__ vo)
{
    __shared__ short L[65536];          // 128 KB
    const int tid = threadIdx.x;
    const int w = tid >> 6, lane = tid & 63, l15 = lane & 15, quad = lane >> 4;
    const int wm = w >> 2, wn = w & 3;
    const int n0 = blockIdx.x * 256, m0 = blockIdx.y * 256;
    const int NT = K >> 6;

    // staging map: thread covers rows (tid>>2) and (tid>>2)+128 of a half,
    // LDS chunk (tid&3); global chunk = (tid&3) ^ (row&3)  (involution)
    const int srow = tid >> 2;
    const int gch8 = ((tid & 3) ^ (srow & 3)) * 8;
    // read-side swizzled chunk (row&3 == l15&3 for all frag rows)
    const int csw8 = (quad ^ (l15 & 3)) * 8;

    floatx4 acc[8][4];
#pragma unroll
    for (int f = 0; f < 8; ++f)
#pragma unroll
        for (int g = 0; g < 4; ++g) acc[f][g] = (floatx4){0.f, 0.f, 0.f, 0.f};

    const short* Ab = A  + (size_t)(m0 + srow) * K + gch8;
    const short* Bb = Bt + (size_t)(n0 + srow) * K + gch8;
    const size_t rj = (size_t)128 * K;

#define STGA(tt, KH, DB) do { \
    const short* s_ = Ab + (size_t)(tt) * 64 + (KH) * 32; \
    short* d_ = L + (DB) * 32768 + (KH) * 8192 + tid * 8; \
    GLL16(s_, d_); GLL16(s_ + rj, d_ + 4096); } while (0)
#define STGB(tt, KH, DB) do { \
    const short* s_ = Bb + (size_t)(tt) * 64 + (KH) * 32; \
    short* d_ = L + (DB) * 32768 + 16384 + (KH) * 8192 + tid * 8; \
    GLL16(s_, d_); GLL16(s_ + rj, d_ + 4096); } while (0)

    // prologue: tile 0 -> buf0, order Ak0,Bk0,Ak1,Bk1 (8 loads)
    STGA(0, 0, 0); STGB(0, 0, 0); STGA(0, 1, 0); STGB(0, 1, 0);
    asm volatile("s_waitcnt vmcnt(4)" ::: "memory");   // Ak0,Bk0 landed
    asm volatile("s_barrier" ::: "memory");

#define PH(KS, FH, STAGE_STMT) do { \
    short8 afr[4], bfr[4]; \
    _Pragma("unroll") \
    for (int i = 0; i < 4; ++i) \
        afr[i] = *(const short8*)(ab + (KS) * 8192 + \
                 (wm * 128 + ((FH) * 4 + i) * 16 + l15) * 32 + csw8); \
    _Pragma("unroll") \
    for (int g = 0; g < 4; ++g) \
        bfr[g] = *(const short8*)(bb + (KS) * 8192 + \
                 (wn * 64 + g * 16 + l15) * 32 + csw8); \
    STAGE_STMT; \
    __builtin_amdgcn_s_setprio(1); \
    _Pragma("unroll") \
    for (int i = 0; i < 4; ++i) { \
        acc[(FH)*4+i][0] = __builtin_amdgcn_mfma_f32_16x16x32_bf16(afr[i], bfr[0], acc[(FH)*4+i][0], 0, 0, 0); \
        acc[(FH)*4+i][1] = __builtin_amdgcn_mfma_f32_16x16x32_bf16(afr[i], bfr[1], acc[(FH)*4+i][1], 0, 0, 0); \
        acc[(FH)*4+i][2] = __builtin_amdgcn_mfma_f32_16x16x32_bf16(afr[i], bfr[2], acc[(FH)*4+i][2], 0, 0, 0); \
        acc[(FH)*4+i][3] = __builtin_amdgcn_mfma_f32_16x16x32_bf16(afr[i], bfr[3], acc[(FH)*4+i][3], 0, 0, 0); \
    } \
    __builtin_amdgcn_s_setprio(0); } while (0)

#define PHW \
    asm volatile("s_waitcnt vmcnt(4)" ::: "memory"); \
    asm volatile("s_barrier" ::: "memory");

    for (int t = 0; t < NT - 1; ++t) {
        const int cur = t & 1, nxt = cur ^ 1;
        const short* ab = L + cur * 32768;
        const short* bb = ab + 16384;
        PH(0, 0, STGA(t + 1, 0, nxt)); PHW;
        PH(0, 1, STGB(t + 1, 0, nxt)); PHW;
        PH(1, 0, STGA(t + 1, 1, nxt)); PHW;
        PH(1, 1, STGB(t + 1, 1, nxt)); PHW;
    }
    // last tile: drain once, then compute-only
    asm volatile("s_waitcnt vmcnt(0)" ::: "memory");
    asm volatile("s_barrier" ::: "memory");
    {
        const int cur = (NT - 1) & 1;
        const short* ab = L + cur * 32768;
        const short* bb = ab + 16384;
        PH(0, 0, (void)0); PH(0, 1, (void)0);
        PH(1, 0, (void)0); PH(1, 1, (void)0);
    }

    // ---- epilogue
    if (!qkvmode) {
#pragma unroll
        for (int f = 0; f < 8; ++f) {
            int grow = m0 + wm * 128 + f * 16 + quad * 4;
#pragma unroll
            for (int g = 0; g < 4; ++g) {
                int gcol = n0 + wn * 64 + g * 16 + l15;
                float bvv = b0[gcol];
                floatx4 v = acc[f][g];
#pragma unroll
                for (int r = 0; r < 4; ++r)
                    Cf[(size_t)(grow + r) * N + gcol] = v[r] + bvv;
            }
        }
    } else {
#pragma unroll
        for (int g = 0; g < 4; ++g) {
            int gcol = n0 + wn * 64 + g * 16 + l15;
            float bvv = (gcol < 2048) ? b0[gcol]
                      : (gcol < 2560) ? b1[gcol - 2048] : b2[gcol - 2560];
#pragma unroll
            for (int f = 0; f < 8; ++f) {
                int grow = m0 + wm * 128 + f * 16 + quad * 4;
                floatx4 v = acc[f][g];
                if (n0 < 2048) {
#pragma unroll
                    for (int r = 0; r < 4; ++r)
                        qo[(size_t)(grow + r) * 2048 + gcol] = f2bf(v[r] + bvv);
                } else if (n0 < 2560) {
                    int c = gcol - 2048;
#pragma unroll
                    for (int r = 0; r < 4; ++r)
                        ko[(size_t)(grow + r) * 512 + c] = f2bf(v[r] + bvv);
                } else {
                    int c = gcol - 2560, gg = c >> 7, dv = c & 127;
                    int bb2 = grow >> 11, s = grow & 2047;
                    uint2 pk;
                    pk.x = pkr(v[0] + bvv, v[1] + bvv);
                    pk.y = pkr(v[2] + bvv, v[3] + bvv);
                    *(uint2*)&vo[(((size_t)bb2 * G_ + gg) * HD_ + dv) * S_ + s] = pk;
                }
            }
        }
    }
#undef PH
#undef PHW
#undef STGA
#undef STGB
}

// ---------------------------------------------------------------------------
// RoPE in-place on bf16 (B,S,nh,HD); fp32 trig (err 1e-4 << bf16 ulp)
// Q additionally pre-scaled by 1/sqrt(HD) * log2(e): attention softmax runs
// in the exp2 domain (v_exp_f32 computes 2^x natively; saves a v_mul per exp).
// ---------------------------------------------------------------------------
__global__ void rope_bf16_kernel(short* __restrict__ p, int nh, float scale,
                                 int total)
{
    int gid = blockIdx.x * 256 + threadIdx.x;
    if (gid >= total) return;
    int i = gid & 63;
    int rest = gid >> 6;
    int head = rest % nh;
    int rest2 = rest / nh;
    int s = rest2 & (S_ - 1);
    int b = rest2 >> 11;
    size_t base = (((size_t)b * S_ + s) * nh + head) * HD_;
    float inv = __expf((float)i * -0.14391156509f);   // ln(1e4)/64
    float ang = (float)s * inv;
    float sn, cs;
    sincosf(ang, &sn, &cs);
    float t1 = b2f(p[base + i]), t2 = b2f(p[base + 64 + i]);
    p[base + i]      = f2bf((t1 * cs - t2 * sn) * scale);
    p[base + 64 + i] = f2bf((t2 * cs + t1 * sn) * scale);
}

// ---------------------------------------------------------------------------
// MFMA flash attention v7 = v6 (balanced remap + exp2 + defer-max, 214us)
// + T14 async reg-staging + T5 setprio around both MFMA clusters.
// Staging: issue next tile's K/V global->reg at iteration top (latency hides
// under current tile's compute); after compute, lgkmcnt(0)+raw barrier
// (all waves done READING Ks/Vs), ds_write the regs, lgkmcnt(0)+raw barrier
// (tile visible). No global_load_lds -> no forced vmcnt(0) drain anywhere.
// Same data placement as v6 (swizzled global src, linear LDS dest).
// ---------------------------------------------------------------------------
#define PPITCH 72   // shorts; 144B = 16B-aligned, 4-bank stride -> 2-way

__global__ __launch_bounds__(256) void attn_mfma2(
    short* __restrict__ qb, const short* __restrict__ kb,
    const short* __restrict__ vt)
{
    __shared__ short Ks[64 * 128];      // [key][16B-chunk], chunk ^= key&7
    __shared__ short Vs[128 * 64];      // [dv][16B-chunk],  chunk ^= dv&7
    __shared__ short Ps[4][32 * PPITCH];// per-wave P as [q][key]

    const int tid = threadIdx.x;
    const int w = tid >> 6, lane = tid & 63, l15 = lane & 15, quad = lane >> 4;
    // ---- load-balanced qi remap
    const int id = (int)blockIdx.x;
    const int j = id >> 6, grp = j >> 2, pos = j & 3;
    const int qi = (grp == 0) ? (15 - pos)
                 : (grp == 1) ? pos
                 : (grp == 2) ? (11 - pos) : (4 + pos);
    const int q0 = qi * 128;
    const int bh = id & 63, b = bh >> 4, h = bh & 15, g = h >> 2;

    // Q fragments: rows q0 + w*32 + qs*16 + l15, d = quad*8 + 32c
    const short* qp = qb + ((((size_t)b * S_) + q0 + w * 32 + l15) * H_ + h) * HD_
                      + quad * 8;
    short8 qf[2][4];
#pragma unroll
    for (int qs = 0; qs < 2; ++qs)
#pragma unroll
        for (int c = 0; c < 4; ++c)
            qf[qs][c] = *(const short8*)(qp + qs * 16 * (H_ * HD_) + c * 32);

    floatx4 ot[2][8];
#pragma unroll
    for (int qs = 0; qs < 2; ++qs)
#pragma unroll
        for (int s = 0; s < 8; ++s) ot[qs][s] = (floatx4){0.f, 0.f, 0.f, 0.f};
    float m_i[2] = {-1e30f, -1e30f}, l_i[2] = {0.f, 0.f};

    // staging maps (same placement as GLL16 path: per-thread swizzled GLOBAL
    // source, linear LDS dest (256*i + tid)*8)
    const int kkey = tid >> 4, kch = tid & 15;
    const int ksrc = kch ^ (kkey & 7);            // (key+16i)&7 == kkey&7
    const short* kgb = kb + (((size_t)b * S_) * G_ + g) * HD_ + ksrc * 8;
    const int vdv = tid >> 3, vch = tid & 7;
    const int vsrc = vch ^ (vdv & 7);             // (dv+32i)&7 == vdv&7
    const short* vgb = vt + (((size_t)(b * G_ + g)) * HD_ + vdv) * (size_t)S_
                       + vsrc * 8;
    const int sw = l15 & 7;
    short* pw = Ps[w];

    const int nkt = 2 * (qi + 1);

    // ---- prologue: stage tile 0 through regs
    short8 kr[4], vr[4];
#pragma unroll
    for (int i = 0; i < 4; ++i)
        kr[i] = *(const short8*)(kgb + (size_t)(kkey + 16 * i) * (G_ * HD_));
#pragma unroll
    for (int i = 0; i < 4; ++i)
        vr[i] = *(const short8*)(vgb + (size_t)(32 * i) * S_);
#pragma unroll
    for (int i = 0; i < 4; ++i) {
        *(short8*)(Ks + (256 * i + tid) * 8) = kr[i];
        *(short8*)(Vs + (256 * i + tid) * 8) = vr[i];
    }
    asm volatile("s_waitcnt lgkmcnt(0)" ::: "memory");
    __builtin_amdgcn_s_barrier();
    asm volatile("" ::: "memory");

    for (int kt = 0; kt < nkt; ++kt) {
        // ---- issue next tile's global loads NOW; land during compute
        if (kt + 1 < nkt) {
            const short* kg1 = kgb + (size_t)((kt + 1) * 64) * (G_ * HD_);
            const short* vg1 = vgb + (kt + 1) * 64;
#pragma unroll
            for (int i = 0; i < 4; ++i)
                kr[i] = *(const short8*)(kg1 + (size_t)(kkey + 16 * i) * (G_ * HD_));
#pragma unroll
            for (int i = 0; i < 4; ++i)
                vr[i] = *(const short8*)(vg1 + (size_t)(32 * i) * S_);
        }

        // ---- S^T tiles: sa[qs][ksub], row = key = ksub*16+quad*4+r, col = q = l15
        floatx4 sa[2][4];
#pragma unroll
        for (int qs = 0; qs < 2; ++qs)
#pragma unroll
            for (int ks = 0; ks < 4; ++ks) sa[qs][ks] = (floatx4){0.f, 0.f, 0.f, 0.f};
        __builtin_amdgcn_s_setprio(1);
#pragma unroll
        for (int c = 0; c < 4; ++c)
#pragma unroll
            for (int ks = 0; ks < 4; ++ks) {
                short8 kf = *(const short8*)(Ks +
                    ((l15 + 16 * ks) * 16 + ((c * 4 + quad) ^ sw)) * 8);
                sa[0][ks] = __builtin_amdgcn_mfma_f32_16x16x32_bf16(
                    kf, qf[0][c], sa[0][ks], 0, 0, 0);
                sa[1][ks] = __builtin_amdgcn_mfma_f32_16x16x32_bf16(
                    kf, qf[1][c], sa[1][ks], 0, 0, 0);
            }
        __builtin_amdgcn_s_setprio(0);

        const int kbase = kt * 64;
#pragma unroll
        for (int qs = 0; qs < 2; ++qs) {
            const int qrow = q0 + w * 32 + qs * 16 + l15;
            // causal mask (only near diagonal; uniform per qs)
            if (kbase + 63 > q0 + w * 32 + qs * 16) {
#pragma unroll
                for (int ks = 0; ks < 4; ++ks)
#pragma unroll
                    for (int r = 0; r < 4; ++r)
                        if (kbase + ks * 16 + quad * 4 + r > qrow)
                            sa[qs][ks][r] = -1e30f;
            }
            // ---- lane-local online softmax (exp2 domain) over 16 keys + 2 shfl
            float mx = -1e30f;
#pragma unroll
            for (int ks = 0; ks < 4; ++ks)
#pragma unroll
                for (int r = 0; r < 4; ++r) mx = fmaxf(mx, sa[qs][ks][r]);
            mx = fmaxf(mx, __shfl_xor(mx, 16));
            mx = fmaxf(mx, __shfl_xor(mx, 32));
            float mo = m_i[qs];
            // defer-max: only rescale when some lane's max outgrew by >11.5 bits
            if (!__all(mx - mo <= 11.5f)) {
                float mn = fmaxf(mo, mx);
                float al = exp2f(mo - mn);
                m_i[qs] = mn;
                l_i[qs] *= al;
#pragma unroll
                for (int s = 0; s < 8; ++s) {
                    floatx4 o = ot[qs][s];
                    o[0] *= al; o[1] *= al; o[2] *= al; o[3] *= al;
                    ot[qs][s] = o;
                }
                mo = mn;
            }
            float s0 = 0.f, s1 = 0.f, s2 = 0.f, s3 = 0.f;
#pragma unroll
            for (int ks = 0; ks < 4; ++ks) {
                float p0 = exp2f(sa[qs][ks][0] - mo);
                float p1 = exp2f(sa[qs][ks][1] - mo);
                float p2 = exp2f(sa[qs][ks][2] - mo);
                float p3 = exp2f(sa[qs][ks][3] - mo);
                sa[qs][ks][0] = p0; sa[qs][ks][1] = p1;
                sa[qs][ks][2] = p2; sa[qs][ks][3] = p3;
                s0 += p0; s1 += p1; s2 += p2; s3 += p3;
            }
            float sum = (s0 + s1) + (s2 + s3);
            sum += __shfl_xor(sum, 16);
            sum += __shfl_xor(sum, 32);
            l_i[qs] += sum;
            // ---- P -> per-wave LDS as [q][key] (b64 writes)
            short* pr = pw + (qs * 16 + l15) * PPITCH;
#pragma unroll
            for (int ks = 0; ks < 4; ++ks) {
                uint2 pkv;
                pkv.x = pk2(sa[qs][ks][0], sa[qs][ks][1]);
                pkv.y = pk2(sa[qs][ks][2], sa[qs][ks][3]);
                *(uint2*)(pr + ks * 16 + quad * 4) = pkv;
            }
        }

        // ---- O^T += V^T · P^T  (V-frags shared across both q-subtiles)
#pragma unroll
        for (int kc = 0; kc < 2; ++kc) {
            short8 pf0 = *(const short8*)(pw + l15 * PPITCH + kc * 32 + quad * 8);
            short8 pf1 = *(const short8*)(pw + (16 + l15) * PPITCH + kc * 32 + quad * 8);
            __builtin_amdgcn_s_setprio(1);
#pragma unroll
            for (int s = 0; s < 8; ++s) {
                short8 vf = *(const short8*)(Vs +
                    ((l15 + 16 * s) * 8 + ((kc * 4 + quad) ^ sw)) * 8);
                ot[0][s] = __builtin_amdgcn_mfma_f32_16x16x32_bf16(
                    vf, pf0, ot[0][s], 0, 0, 0);
                ot[1][s] = __builtin_amdgcn_mfma_f32_16x16x32_bf16(
                    vf, pf1, ot[1][s], 0, 0, 0);
            }
            __builtin_amdgcn_s_setprio(0);
        }

        // ---- all waves done READING Ks/Vs -> overwrite with prefetched regs
        asm volatile("s_waitcnt lgkmcnt(0)" ::: "memory");
        __builtin_amdgcn_s_barrier();
        asm volatile("" ::: "memory");
        if (kt + 1 < nkt) {
#pragma unroll
            for (int i = 0; i < 4; ++i) {
                *(short8*)(Ks + (256 * i + tid) * 8) = kr[i];
                *(short8*)(Vs + (256 * i + tid) * 8) = vr[i];
            }
        }
        asm volatile("s_waitcnt lgkmcnt(0)" ::: "memory");
        __builtin_amdgcn_s_barrier();
        asm volatile("" ::: "memory");
    }

    // ---- epilogue: normalize (lane-local l), write bf16 in-place
#pragma unroll
    for (int qs = 0; qs < 2; ++qs) {
        float inv = 1.f / l_i[qs];
        size_t base = ((((size_t)b * S_) + q0 + w * 32 + qs * 16 + l15) * H_ + h)
                      * HD_;
#pragma unroll
        for (int s = 0; s < 8; ++s) {
            uint2 pkv;
            pkv.x = pkr(ot[qs][s][0] * inv, ot[qs][s][1] * inv);
            pkv.y = pkr(ot[qs][s][2] * inv, ot[qs][s][3] * inv);
            *(uint2*)&qb[base + s * 16 + quad * 4] = pkv;
        }
    }
}

// ---------------------------------------------------------------------------
extern "C" void kernel_launch(void* const* d_in, const int* in_sizes, int n_in,
                              void* d_out, int out_size, void* d_ws, size_t ws_size,
                              hipStream_t stream)
{
    const float* x  = (const float*)d_in[0];
    const float* Wq = (const float*)d_in[1];
    const float* bq = (const float*)d_in[2];
    const float* Wk = (const float*)d_in[3];
    const float* bk = (const float*)d_in[4];
    const float* Wv = (const float*)d_in[5];
    const float* bv = (const float*)d_in[6];
    const float* Wo = (const float*)d_in[7];
    const float* bo = (const float*)d_in[8];
    float* out = (float*)d_out;

    // ws layout (bf16 elements); total 96.5 MB
    short* xb  = (short*)d_ws;        // 16,777,216
    short* Wt  = xb + 16777216;       // 3072*2048 = 6,291,456 (reused for Wo^T)
    short* qb8 = Wt + 6291456;        // 16,777,216 (q -> attn out, in-place)
    short* kb8 = qb8 + 16777216;      // 4,194,304
    short* vt8 = kb8 + 4194304;       // 4,194,304  V^T (b,g,dv,s)

    const int M = B_ * S_;
    dim3 blk(256);

    cvt_bf16_kernel<<<8192, blk, 0, stream>>>(x, xb, 16777216 / 8);
    tr_bf16_kernel<<<dim3(64, 64), blk, 0, stream>>>(Wq, Wt, 2048, 2048);
    tr_bf16_kernel<<<dim3(16, 64), blk, 0, stream>>>(Wk, Wt + (size_t)2048 * 2048, 2048, 512);
    tr_bf16_kernel<<<dim3(16, 64), blk, 0, stream>>>(Wv, Wt + (size_t)2560 * 2048, 2048, 512);

    // merged QKV GEMM: 256^2 8-phase, grid (N/256, M/256)
    gemm256_8ph<<<dim3(12, 32), dim3(512), 0, stream>>>(
        xb, Wt, M, 3072, 2048, 1, bq, bk, bv, nullptr, qb8, kb8, vt8);

    // Wt slot free now -> Wo^T (stream-ordered)
    tr_bf16_kernel<<<dim3(64, 64), blk, 0, stream>>>(Wo, Wt, 2048, 2048);

    // Q scale folds 1/sqrt(128) * log2(e): softmax runs in exp2 domain
    const float qscale = 0.12751744417f;
    rope_bf16_kernel<<<32768, blk, 0, stream>>>(qb8, H_, qscale, M * H_ * 64);
    rope_bf16_kernel<<<8192,  blk, 0, stream>>>(kb8, G_, 1.0f,   M * G_ * 64);

    attn_mfma2<<<dim3(1024), blk, 0, stream>>>(qb8, kb8, vt8);

    // O-projection: 256^2 8-phase, grid (8, 32); id%8 = bx -> per-XCD B-panel
    gemm256_8ph<<<dim3(8, 32), dim3(512), 0, stream>>>(
        qb8, Wt, M, 2048, 2048, 0, bo, nullptr, nullptr, out,
        nullptr, nullptr, nullptr);
}